// Round 11
// baseline (726.200 us; speedup 1.0000x reference)
//
#include <hip/hip_runtime.h>
#include <stdint.h>

typedef unsigned short u16;
typedef unsigned int u32;
typedef __attribute__((ext_vector_type(8))) __bf16 bf16x8;
typedef __attribute__((ext_vector_type(4))) float f32x4;

#define DEVINL __device__ __forceinline__

DEVINL float bf2f(u16 u){ union{u32 i; float f;} c; c.i = ((u32)u)<<16; return c.f; }
DEVINL u16 f2bf(float f){ union{float f; u32 i;} c; c.f=f; u32 u=c.i; return (u16)((u + 0x7fffu + ((u>>16)&1u))>>16); }
DEVINL u32 pack2(float a, float b){ return (u32)f2bf(a) | ((u32)f2bf(b)<<16); }
DEVINL float sq2(u32 u){ float a = bf2f((u16)(u&0xffffu)), b = bf2f((u16)(u>>16)); return a*a + b*b; }

// parity of sign(e_a * e_b) in Cl(4,1): reorder swaps + metric (e4^2 = -1)
DEVINL int sign_neg(int a, int b){
  int s = __popc((a>>1)&b) + __popc((a>>2)&b) + __popc((a>>3)&b) + __popc((a>>4)&b) + ((a&b)>>4);
  return s & 1;
}

constexpr u32 sgn_mask(int m){
  u32 r = 0;
  for (int n=0;n<32;n++){
    int s = __builtin_popcount((m>>1)&n) + __builtin_popcount((m>>2)&n)
          + __builtin_popcount((m>>3)&n) + __builtin_popcount((m>>4)&n) + ((m&n)>>4);
    r |= (u32)(s&1) << n;
  }
  return r;
}
__device__ __constant__ u32 SGNC[32] = {
  sgn_mask(0), sgn_mask(1), sgn_mask(2), sgn_mask(3), sgn_mask(4), sgn_mask(5), sgn_mask(6), sgn_mask(7),
  sgn_mask(8), sgn_mask(9), sgn_mask(10),sgn_mask(11),sgn_mask(12),sgn_mask(13),sgn_mask(14),sgn_mask(15),
  sgn_mask(16),sgn_mask(17),sgn_mask(18),sgn_mask(19),sgn_mask(20),sgn_mask(21),sgn_mask(22),sgn_mask(23),
  sgn_mask(24),sgn_mask(25),sgn_mask(26),sgn_mask(27),sgn_mask(28),sgn_mask(29),sgn_mask(30),sgn_mask(31)};

DEVINL void gload_lds16(const void* g, void* l){
  __builtin_amdgcn_global_load_lds(
    (const __attribute__((address_space(1))) void*)g,
    (__attribute__((address_space(3))) void*)l, 16, 0, 0);
}

// ---------------- transpose x: [bs][i=256][n=32] f32 -> xt [bs*32+n][i] bf16 -----
__global__ __launch_bounds__(256) void k_tr_x(const float* __restrict__ x, u16* __restrict__ xt){
  __shared__ float tile[256][33];
  const int bs = blockIdx.x, t = threadIdx.x;
  const float* xp = x + (size_t)bs*8192 + t*32;
  #pragma unroll
  for (int n=0;n<32;n+=4){
    float4 v = *(const float4*)(xp + n);
    tile[t][n]=v.x; tile[t][n+1]=v.y; tile[t][n+2]=v.z; tile[t][n+3]=v.w;
  }
  __syncthreads();
  const int n = t>>3, i0 = (t&7)*32;
  u16* dst = xt + ((size_t)bs*32 + n)*256 + i0;
  #pragma unroll
  for (int q=0;q<4;q++){
    u32 w0 = pack2(tile[i0+q*8+0][n], tile[i0+q*8+1][n]);
    u32 w1 = pack2(tile[i0+q*8+2][n], tile[i0+q*8+3][n]);
    u32 w2 = pack2(tile[i0+q*8+4][n], tile[i0+q*8+5][n]);
    u32 w3 = pack2(tile[i0+q*8+6][n], tile[i0+q*8+7][n]);
    *(uint4*)(dst + q*8) = make_uint4(w0,w1,w2,w3);
  }
}

// ---------------- transpose w into MFMA-fragment order -----------------------------
// wT3[wsel][m][q][o_blk][kk][lane][e]: lane = (o&15) + k8*16, i = q*64+kk*32+k8*8+e
__global__ __launch_bounds__(256) void k_tr_w(const float* __restrict__ wq, const float* __restrict__ wk,
                                              const float* __restrict__ wv, const float* __restrict__ wo,
                                              u16* __restrict__ wT3){
  __shared__ float tile[256][33];
  const int bid = blockIdx.x, t = threadIdx.x;
  const int wsel = bid>>8, o = bid&255;
  const float* w = wsel==0?wq: wsel==1?wk: wsel==2?wv: wo;
  const float* wp = w + ((size_t)o*256 + t)*32;
  #pragma unroll
  for (int m=0;m<32;m+=4){
    float4 v = *(const float4*)(wp + m);
    tile[t][m]=v.x; tile[t][m+1]=v.y; tile[t][m+2]=v.z; tile[t][m+3]=v.w;
  }
  __syncthreads();
  const int m = t>>3, sub = t&7;
  const int q = sub>>1, kk = sub&1;
  const int c = o&15, obk = o>>4;
  const size_t base = (((((size_t)wsel*32 + m)*4 + q)*16 + obk)*2 + kk)*512;
  #pragma unroll
  for (int k8=0;k8<4;k8++){
    const int i0 = sub*32 + k8*8;
    u32 w0 = pack2(tile[i0+0][m], tile[i0+1][m]);
    u32 w1 = pack2(tile[i0+2][m], tile[i0+3][m]);
    u32 w2 = pack2(tile[i0+4][m], tile[i0+5][m]);
    u32 w3 = pack2(tile[i0+6][m], tile[i0+7][m]);
    *(uint4*)(wT3 + base + (size_t)(c + k8*16)*8) = make_uint4(w0,w1,w2,w3);
  }
}

// ---- geo GEMM helpers -------------------------------------------------------------
DEVINL void geo_loadB(const u16* __restrict__ Wm, const int (&boff)[4][2], uint4 (&Br)[8]){
  #pragma unroll
  for (int fn=0; fn<4; ++fn){
    #pragma unroll
    for (int kk=0; kk<2; ++kk)
      Br[fn*2+kk] = *(const uint4*)(Wm + boff[fn][kk]);
  }
}

DEVINL void geo_compute(int m, const char* __restrict__ Ab, const uint4 (&Br)[8],
                        f32x4 (&acc)[4][4], const int (&baseA)[4][2], const u32 (&sgnw)[4]){
  const int dlt = (m<<7) | ((m&7)<<4);
  bf16x8 af[4][2];
  #pragma unroll
  for (int f=0; f<4; ++f){
    const int soff = (int)((sgnw[f] >> m) & 1u) << 14;
    #pragma unroll
    for (int kk=0; kk<2; ++kk)
      af[f][kk] = *(const bf16x8*)(Ab + ((baseA[f][kk] ^ dlt) | soff));
  }
  __builtin_amdgcn_s_setprio(1);
  #pragma unroll
  for (int kk=0; kk<2; ++kk){
    #pragma unroll
    for (int fm=0;fm<4;fm++){
      #pragma unroll
      for (int fn=0;fn<4;fn++)
        acc[fm][fn] = __builtin_amdgcn_mfma_f32_16x16x32_bf16(
            af[fm][kk], *(const bf16x8*)&Br[fn*2+kk], acc[fm][fn], 0,0,0);
    }
  }
  __builtin_amdgcn_s_setprio(0);
}

// geo GEMM: out[bs,o,l] = sum_{m,i} xt[bs,l^m,i]*sign(m,l^m)*wT[m][o][i]
// 128x128 tile, 4 waves (2x2). A i-quarter LDS-resident in DUAL-SIGN form;
// per-m blade perm+sign is pure addressing. B streamed global->registers with
// a 2-deep named double-buffer prefetch (load m+2 while computing m).
template<int EPI>
__global__ __launch_bounds__(256) void k_geo_gemm(const u16* __restrict__ xt, const u16* __restrict__ wT3,
                                                  u16* __restrict__ qkv, float* __restrict__ dout,
                                                  float* __restrict__ Nq, float* __restrict__ Nk){
  constexpr int NT = (EPI==0)?6:2;
  constexpr int NWG = 256*NT;
  __shared__ __align__(16) u16 Apan[2*128*64];   // 32 KB: +A | -A
  const int wg = blockIdx.x;
  const int bid = (wg&7)*(NWG/8) + (wg>>3);      // bijective XCD chunking, tn-major
  const int tn = bid >> 8;
  const int tm = bid & 255;
  const int row0 = tm*128, col0 = tn*128;
  const int wsel = (EPI==0)? (col0>>8) : 3;
  const int o0   = (EPI==0)? (col0&255) : col0;
  const u16* Wp = wT3 + (size_t)wsel*2097152;    // panel base (u16)
  const int t = threadIdx.x, lane = t&63, wid = t>>6;
  const int wm = wid>>1, wn = wid&1, lo = lane&15, hi = lane>>4;

  // A base byte-offsets (m=0) and per-lane sign words
  int baseA[4][2]; u32 sgnw[4];
  #pragma unroll
  for (int f=0; f<4; ++f){
    const int ra = wm*64 + f*16 + lo;
    #pragma unroll
    for (int kk=0; kk<2; ++kk)
      baseA[f][kk] = ra*128 + (((kk*4+hi) ^ (lo&7))*16);
    const int rl = ra & 31;
    u32 sw = 0;
    for (int m=0;m<32;m++) sw |= ((SGNC[m] >> ((rl^m)&31)) & 1u) << m;
    sgnw[f] = sw;
  }
  // B fragment offsets (u16 units) within a (m,q) super-block
  int boff[4][2];
  #pragma unroll
  for (int fn=0; fn<4; ++fn){
    const int ob = (o0>>4) + wn*4 + fn;
    #pragma unroll
    for (int kk=0; kk<2; ++kk)
      boff[fn][kk] = (ob*2+kk)*512 + lane*8;
  }

  f32x4 acc[4][4];
  #pragma unroll
  for(int a=0;a<4;a++){
    #pragma unroll
    for(int b=0;b<4;b++){ acc[a][b] = (f32x4){0.f,0.f,0.f,0.f}; }
  }
  const char* Ab = (const char*)Apan;

  for (int q=0; q<4; ++q){
    __syncthreads();                 // previous quarter fully consumed
    #pragma unroll
    for (int c=0;c<4;c++){
      const int base = (wid*4+c)*64;
      const int idx = base + lane;
      const int rr = idx>>3, g = idx&7;
      gload_lds16(xt + (size_t)(row0+rr)*256 + q*64 + ((g^(rr&7))*8), Apan + base*8);
    }
    __syncthreads();                 // drain: +A quarter visible
    // build negated copy at +16KB (LDS->LDS, sign-bit XOR)
    #pragma unroll
    for (int c=0;c<4;c++){
      const int idx = c*256 + t;
      uint4 v = *(const uint4*)(Apan + idx*8);
      v.x^=0x80008000u; v.y^=0x80008000u; v.z^=0x80008000u; v.w^=0x80008000u;
      *(uint4*)(Apan + 8192 + idx*8) = v;
    }
    __syncthreads();                 // -A visible
    const u16* Wq = Wp + (size_t)q*16384;
    uint4 Ba[8], Bb[8];
    geo_loadB(Wq + (size_t)0*65536, boff, Ba);
    geo_loadB(Wq + (size_t)1*65536, boff, Bb);
    #pragma unroll 1
    for (int mm=0; mm<16; ++mm){
      const int m0 = 2*mm, m1 = m0+1;
      geo_compute(m0, Ab, Ba, acc, baseA, sgnw);
      if (mm != 15) geo_loadB(Wq + (size_t)(m0+2)*65536, boff, Ba);
      geo_compute(m1, Ab, Bb, acc, baseA, sgnw);
      if (mm != 15) geo_loadB(Wq + (size_t)(m1+2)*65536, boff, Bb);
    }
  }

  // epilogue: normalize each multivector; EPI==0 also emits fused Nq/Nk
  float hacc[2][2] = {{0.f,0.f},{0.f,0.f}};
  #pragma unroll
  for (int fn=0; fn<4; ++fn){
    const int c = col0 + wn*64 + fn*16 + lo;
    float s0=0.f, s1=0.f;
    #pragma unroll
    for (int r=0;r<4;r++){
      s0 += acc[0][fn][r]*acc[0][fn][r] + acc[1][fn][r]*acc[1][fn][r];
      s1 += acc[2][fn][r]*acc[2][fn][r] + acc[3][fn][r]*acc[3][fn][r];
    }
    s0 += __shfl_xor(s0,16); s0 += __shfl_xor(s0,32);
    s1 += __shfl_xor(s1,16); s1 += __shfl_xor(s1,32);
    if constexpr (EPI==0){
      hacc[fn>>1][0] += s0/(s0+1e-6f);
      hacc[fn>>1][1] += s1/(s1+1e-6f);
    }
    const float r0 = rsqrtf(s0+1e-6f), r1 = rsqrtf(s1+1e-6f);
    #pragma unroll
    for (int fm=0;fm<4;fm++){
      const float rs = (fm<2)? r0 : r1;
      const int bsg = (row0>>5) + wm*2 + (fm>>1);
      const int l0 = (fm&1)*16 + hi*4;
      float v0 = acc[fm][fn][0]*rs, v1 = acc[fm][fn][1]*rs, v2 = acc[fm][fn][2]*rs, v3 = acc[fm][fn][3]*rs;
      if constexpr (EPI==0){
        if (c < 256){ // fold SIG_DIAG into q
          if (sign_neg(l0+0,l0+0)) v0=-v0;
          if (sign_neg(l0+1,l0+1)) v1=-v1;
          if (sign_neg(l0+2,l0+2)) v2=-v2;
          if (sign_neg(l0+3,l0+3)) v3=-v3;
        }
        u16* dst = qkv + ((size_t)bsg*768 + c)*32 + l0;
        *(uint2*)dst = make_uint2(pack2(v0,v1), pack2(v2,v3));
      } else {
        float* dst = dout + ((size_t)bsg*256 + c)*32 + l0;
        *(float4*)dst = make_float4(v0,v1,v2,v3);
      }
    }
  }
  if constexpr (EPI==0){
    if (tn < 4){
      #pragma unroll
      for (int hs=0; hs<2; ++hs){
        #pragma unroll
        for (int p=0; p<2; ++p){
          float v = hacc[hs][p];
          v += __shfl_xor(v,1); v += __shfl_xor(v,2);
          v += __shfl_xor(v,4); v += __shfl_xor(v,8);
          hacc[hs][p] = v;
        }
      }
      if (lo==0 && hi==0){
        const int hb = ((col0&255)>>5) + wn*2;
        float* nd = (tn<2)? Nq : Nk;
        #pragma unroll
        for (int hs=0; hs<2; ++hs){
          #pragma unroll
          for (int p=0; p<2; ++p){
            const int bsf = (row0>>5) + wm*2 + p;
            const int b = bsf>>9, s = bsf&511;
            nd[((size_t)(b*8 + hb+hs))*512 + s] = hacc[hs][p];
          }
        }
      }
    }
  }
}

// ---------------- shared 128x128 MFMA tile engine (linear-row operands) -----------
DEVINL void mm_steps(const u16* Abase, int Astride, const u16* Bbase, int Bstride, int ksteps,
                     u16* Al, u16* Bl, f32x4 (&acc)[4][4], int lane, int wid){
  const int wm = wid>>1, wn = wid&1, lo = lane&15, hi = lane>>4;
  for (int s=0; s<ksteps; ++s){
    const int k0 = s*64;
    #pragma unroll
    for (int c=0;c<4;c++){
      const int gb = (wid*4+c)*64;
      const int idx = gb + lane;
      const int r = idx>>3, j = idx&7;
      const int sw = ((j^(r&7))*8);
      gload_lds16(Abase + (size_t)r*Astride + k0 + sw, Al + gb*8);
      gload_lds16(Bbase + (size_t)r*Bstride + k0 + sw, Bl + gb*8);
    }
    __syncthreads();
    #pragma unroll
    for (int kk=0; kk<2; ++kk){
      bf16x8 af[4], bfr[4];
      #pragma unroll
      for (int f=0;f<4;f++){
        const int ra = wm*64 + f*16 + lo;
        const int jc = kk*4 + hi;
        af[f] = *(const bf16x8*)(Al + ra*64 + ((jc^(ra&7))*8));
        const int rb = wn*64 + f*16 + lo;
        bfr[f] = *(const bf16x8*)(Bl + rb*64 + ((jc^(rb&7))*8));
      }
      #pragma unroll
      for (int fm=0;fm<4;fm++){
        #pragma unroll
        for (int fn=0;fn<4;fn++)
          acc[fm][fn] = __builtin_amdgcn_mfma_f32_16x16x32_bf16(af[fm], bfr[fn], acc[fm][fn], 0,0,0);
      }
    }
    __syncthreads();
  }
}

// ---------------- score: ss + gamma*bivector, write S1 f32 and S1T bf16 -----------
__global__ __launch_bounds__(256) void k_score(const u16* __restrict__ qkv, const float* __restrict__ Nq,
                                               const float* __restrict__ Nk, const float* __restrict__ gptr,
                                               float* __restrict__ S1, u16* __restrict__ S1T){
  __shared__ __align__(16) u16 Al[128*64];
  __shared__ __align__(16) u16 Bl[128*64];
  __shared__ __align__(16) u16 Tl[128*136];
  const int wg = blockIdx.x;
  const int bid = (wg&7)*32 + (wg>>3);
  const int bh = bid>>4, ti=(bid>>2)&3, tj=bid&3;
  const int b = bh>>3, h = bh&7;
  const int i0=ti*128, j0=tj*128;
  const int t=threadIdx.x, lane=t&63, wid=t>>6;
  const int wm=wid>>1, wn=wid&1, lo=lane&15, hi=lane>>4;
  f32x4 acc[4][4];
  #pragma unroll
  for(int a=0;a<4;a++){
    #pragma unroll
    for(int c=0;c<4;c++){ acc[a][c] = (f32x4){0.f,0.f,0.f,0.f}; }
  }
  const u16* Abase = qkv + ((size_t)(b*512+i0))*24576 + h*1024;
  const u16* Bbase = qkv + ((size_t)(b*512+j0))*24576 + 8192 + h*1024;
  mm_steps(Abase, 24576, Bbase, 24576, 16, Al, Bl, acc, lane, wid);
  const float gamma = *gptr;
  const float rhd = 0.17677669529663687f; // 1/sqrt(32)
  float nkv[4];
  #pragma unroll
  for (int fn=0;fn<4;fn++) nkv[fn] = Nk[bh*512 + j0 + wn*64 + fn*16 + lo];
  #pragma unroll
  for (int fm=0;fm<4;fm++){
    #pragma unroll
    for (int r=0;r<4;r++){
      const int iL = wm*64 + fm*16 + hi*4 + r;
      const float nq = Nq[bh*512 + i0 + iL];
      #pragma unroll
      for (int fn=0;fn<4;fn++){
        const int jL = wn*64 + fn*16 + lo;
        const float ss = acc[fm][fn][r];
        const float biv = sqrtf(fmaxf(nq*nkv[fn] - ss*ss, 0.f) + 1e-6f);
        const float sc = (ss + gamma*biv)*rhd;
        S1[((size_t)bh*512 + i0 + iL)*512 + j0 + jL] = sc;
        Tl[jL*136 + iL] = f2bf(sc);
      }
    }
  }
  __syncthreads();
  const int jj = t>>1, half = t&1;
  u16* dst = S1T + ((size_t)bh*512 + (j0+jj))*512 + i0 + half*64;
  #pragma unroll
  for (int q=0;q<8;q++)
    *(uint4*)(dst + q*8) = *(const uint4*)(Tl + jj*136 + half*64 + q*8);
}

// ---------------- row softmax, wave-per-row (optionally masked) -------------------
__global__ __launch_bounds__(256) void k_softmax(const float* __restrict__ S, const int* __restrict__ mask,
                                                 u16* __restrict__ P, int masked){
  const int t = threadIdx.x, lane = t&63, wid = t>>6;
  const int row = blockIdx.x*4 + wid;   // bh*512 + i
  const int b = row>>12;
  const float* sp = S + (size_t)row*512;
  float4 a = *(const float4*)(sp + lane*4);
  float4 c = *(const float4*)(sp + 256 + lane*4);
  if (masked){
    const int* mp = mask + b*512;
    int4 ma = *(const int4*)(mp + lane*4);
    int4 mc = *(const int4*)(mp + 256 + lane*4);
    if (ma.x==0) a.x=-1e9f; if (ma.y==0) a.y=-1e9f; if (ma.z==0) a.z=-1e9f; if (ma.w==0) a.w=-1e9f;
    if (mc.x==0) c.x=-1e9f; if (mc.y==0) c.y=-1e9f; if (mc.z==0) c.z=-1e9f; if (mc.w==0) c.w=-1e9f;
  }
  float mx = fmaxf(fmaxf(fmaxf(a.x,a.y),fmaxf(a.z,a.w)), fmaxf(fmaxf(c.x,c.y),fmaxf(c.z,c.w)));
  #pragma unroll
  for (int o=1;o<64;o<<=1) mx = fmaxf(mx, __shfl_xor(mx,o));
  const float e0=__expf(a.x-mx), e1=__expf(a.y-mx), e2=__expf(a.z-mx), e3=__expf(a.w-mx);
  const float e4=__expf(c.x-mx), e5=__expf(c.y-mx), e6=__expf(c.z-mx), e7=__expf(c.w-mx);
  float sm = (e0+e1)+(e2+e3)+(e4+e5)+(e6+e7);
  #pragma unroll
  for (int o=1;o<64;o<<=1) sm += __shfl_xor(sm,o);
  const float inv = 1.f/sm;
  u16* pp = P + (size_t)row*512;
  *(uint2*)(pp + lane*4)       = make_uint2(pack2(e0*inv,e1*inv), pack2(e2*inv,e3*inv));
  *(uint2*)(pp + 256 + lane*4) = make_uint2(pack2(e4*inv,e5*inv), pack2(e6*inv,e7*inv));
}

// ---------------- triangle update: S1 += 0.1 * P1 @ S1b (in place, f32) ----------
__global__ __launch_bounds__(256) void k_tri(const u16* __restrict__ P1, const u16* __restrict__ S1T,
                                             float* __restrict__ S1){
  __shared__ __align__(16) u16 Al[128*64];
  __shared__ __align__(16) u16 Bl[128*64];
  const int wg = blockIdx.x;
  const int bid = (wg&7)*32 + (wg>>3);
  const int bh = bid>>4, ti=(bid>>2)&3, tj=bid&3;
  const int i0=ti*128, j0=tj*128;
  const int t=threadIdx.x, lane=t&63, wid=t>>6;
  const int wm=wid>>1, wn=wid&1, lo=lane&15, hi=lane>>4;
  f32x4 acc[4][4];
  #pragma unroll
  for(int a=0;a<4;a++){
    #pragma unroll
    for(int c=0;c<4;c++){ acc[a][c] = (f32x4){0.f,0.f,0.f,0.f}; }
  }
  const u16* Abase = P1  + ((size_t)bh*512 + i0)*512;
  const u16* Bbase = S1T + ((size_t)bh*512 + j0)*512;
  mm_steps(Abase, 512, Bbase, 512, 8, Al, Bl, acc, lane, wid);
  #pragma unroll
  for (int fm=0;fm<4;fm++){
    #pragma unroll
    for (int r=0;r<4;r++){
      const int iL = wm*64 + fm*16 + hi*4 + r;
      #pragma unroll
      for (int fn=0;fn<4;fn++){
        const int jL = wn*64 + fn*16 + lo;
        const size_t idx = ((size_t)bh*512 + i0 + iL)*512 + j0 + jL;
        S1[idx] = S1[idx] + 0.1f*acc[fm][fn][r];
      }
    }
  }
}

// ---------------- transpose V to VT[bh][d][s] ------------------------------------
__global__ __launch_bounds__(256) void k_tr_v(const u16* __restrict__ qkv, u16* __restrict__ VT){
  __shared__ u16 tile[128*129];
  const int bid=blockIdx.x;
  const int bh = bid>>5, dch=(bid>>2)&7, sch=bid&3;
  const int b=bh>>3, h=bh&7;
  const int d0=dch*128, s0=sch*128;
  const int t=threadIdx.x;
  {
    const int r=t>>1, half=t&1;
    const u16* src = qkv + ((size_t)(b*512+s0+r))*24576 + 16384 + h*1024 + d0 + half*64;
    #pragma unroll
    for (int q=0;q<8;q++){
      uint4 v = *(const uint4*)(src + q*8);
      u16* dp = tile + r*129 + half*64 + q*8;
      dp[0]=(u16)(v.x&0xffffu); dp[1]=(u16)(v.x>>16); dp[2]=(u16)(v.y&0xffffu); dp[3]=(u16)(v.y>>16);
      dp[4]=(u16)(v.z&0xffffu); dp[5]=(u16)(v.z>>16); dp[6]=(u16)(v.w&0xffffu); dp[7]=(u16)(v.w>>16);
    }
  }
  __syncthreads();
  {
    const int rr=t>>1, half=t&1;
    u16* dst = VT + ((size_t)bh*1024 + d0+rr)*512 + s0 + half*64;
    #pragma unroll
    for (int q=0;q<4;q++){
      u32 w[8];
      #pragma unroll
      for (int e=0;e<8;e++){
        const int s = half*64 + q*16 + e*2;
        w[e] = (u32)tile[s*129+rr] | ((u32)tile[(s+1)*129+rr]<<16);
      }
      *(uint4*)(dst + q*16)     = make_uint4(w[0],w[1],w[2],w[3]);
      *(uint4*)(dst + q*16 + 8) = make_uint4(w[4],w[5],w[6],w[7]);
    }
  }
}

// ---------------- PV: out = P2 @ V, write transposed xt2[bs*32+l][e] bf16 --------
__global__ __launch_bounds__(256) void k_pv(const u16* __restrict__ P2, const u16* __restrict__ VT,
                                            u16* __restrict__ xt2){
  __shared__ __align__(16) u16 Al[128*64];
  __shared__ __align__(16) u16 Bl[128*64];
  __shared__ __align__(16) u16 Tl[128*136];
  const int wg = blockIdx.x;
  const int bid = (wg&7)*64 + (wg>>3);
  const int bh = bid>>5, ti=(bid>>3)&3, td=bid&7;
  const int b=bh>>3, h=bh&7;
  const int i0=ti*128, d0=td*128;
  const int t=threadIdx.x, lane=t&63, wid=t>>6;
  const int wm=wid>>1, wn=wid&1, lo=lane&15, hi=lane>>4;
  f32x4 acc[4][4];
  #pragma unroll
  for(int a=0;a<4;a++){
    #pragma unroll
    for(int c=0;c<4;c++){ acc[a][c] = (f32x4){0.f,0.f,0.f,0.f}; }
  }
  const u16* Abase = P2 + ((size_t)bh*512 + i0)*512;
  const u16* Bbase = VT + ((size_t)bh*1024 + d0)*512;
  mm_steps(Abase, 512, Bbase, 512, 8, Al, Bl, acc, lane, wid);
  #pragma unroll
  for (int fm=0;fm<4;fm++){
    #pragma unroll
    for (int r=0;r<4;r++){
      const int sL = wm*64 + fm*16 + hi*4 + r;
      #pragma unroll
      for (int fn=0;fn<4;fn++){
        const int dL = wn*64 + fn*16 + lo;
        Tl[sL*136 + dL] = f2bf(acc[fm][fn][r]);
      }
    }
  }
  __syncthreads();
  const int hd0 = td*4;
  #pragma unroll
  for (int u=0;u<16;u++){
    const int seg = t + u*256;
    const int sL = seg>>5, l = seg&31;
    const u16* tp = Tl + sL*136 + l;
    u32 w0 = (u32)tp[0]  | ((u32)tp[32]<<16);
    u32 w1 = (u32)tp[64] | ((u32)tp[96]<<16);
    u16* dst = xt2 + ((size_t)((b*512 + i0 + sL)*32 + l))*256 + h*32 + hd0;
    *(uint2*)dst = make_uint2(w0,w1);
  }
}

extern "C" void kernel_launch(void* const* d_in, const int* in_sizes, int n_in,
                              void* d_out, int out_size, void* d_ws, size_t ws_size,
                              hipStream_t stream) {
  const float* x  = (const float*)d_in[0];
  const float* wq = (const float*)d_in[1];
  const float* wk = (const float*)d_in[2];
  const float* wv = (const float*)d_in[3];
  const float* wo = (const float*)d_in[4];
  const float* gamma = (const float*)d_in[5];
  const int*   mask  = (const int*)d_in[6];
  float* out = (float*)d_out;

  char* ws = (char*)d_ws;
  size_t off = 0;
  auto alloc = [&](size_t n){ char* p = ws + off; off += (n + 255) & ~(size_t)255; return p; };
  u16*  xt  = (u16*) alloc(16777216);   // [32768][256] bf16
  u16*  wT3 = (u16*) alloc(16777216);   // [4][32][4][16][2][64][8] bf16 fragment-order
  u16*  qkv = (u16*) alloc(50331648);   // [1024][768][32] bf16
  float* Nq = (float*)alloc(32768);
  float* Nk = (float*)alloc(32768);
  float* S1 = (float*)alloc(16777216);  // [16][512][512] f32
  u16*  S1T = (u16*) alloc(8388608);    // [16][512][512] bf16 (transposed)
  u16*  P2  = (u16*) alloc(8388608);
  u16*  VT  = (u16*) alloc(16777216);   // [16][1024][512] bf16
  u16*  P1  = xt;                       // alias: xt dead after gemm<0>; P1 dead before k_pv writes xt2
  u16*  xt2 = xt;                       // alias: reuse xt region for attention output

  k_tr_x<<<1024, 256, 0, stream>>>(x, xt);
  k_tr_w<<<1024, 256, 0, stream>>>(wq, wk, wv, wo, wT3);
  k_geo_gemm<0><<<1536, 256, 0, stream>>>(xt, wT3, qkv, nullptr, Nq, Nk);
  k_score<<<256, 256, 0, stream>>>(qkv, Nq, Nk, gamma, S1, S1T);
  k_softmax<<<2048, 256, 0, stream>>>(S1, mask, P1, 0);
  k_tri<<<256, 256, 0, stream>>>(P1, S1T, S1);
  k_softmax<<<2048, 256, 0, stream>>>(S1, mask, P2, 1);
  k_tr_v<<<512, 256, 0, stream>>>(qkv, VT);
  k_pv<<<512, 256, 0, stream>>>(P2, VT, xt2);
  k_geo_gemm<1><<<512, 256, 0, stream>>>(xt2, wT3, nullptr, out, nullptr, nullptr);
}

// Round 12
// 540.622 us; speedup vs baseline: 1.3433x; 1.3433x over previous
//
#include <hip/hip_runtime.h>
#include <stdint.h>

typedef unsigned short u16;
typedef unsigned int u32;
typedef __attribute__((ext_vector_type(8))) __bf16 bf16x8;
typedef __attribute__((ext_vector_type(4))) float f32x4;

#define DEVINL __device__ __forceinline__

DEVINL float bf2f(u16 u){ union{u32 i; float f;} c; c.i = ((u32)u)<<16; return c.f; }
DEVINL u16 f2bf(float f){ union{float f; u32 i;} c; c.f=f; u32 u=c.i; return (u16)((u + 0x7fffu + ((u>>16)&1u))>>16); }
DEVINL u32 pack2(float a, float b){ return (u32)f2bf(a) | ((u32)f2bf(b)<<16); }
DEVINL float sq2(u32 u){ float a = bf2f((u16)(u&0xffffu)), b = bf2f((u16)(u>>16)); return a*a + b*b; }

// parity of sign(e_a * e_b) in Cl(4,1): reorder swaps + metric (e4^2 = -1)
DEVINL int sign_neg(int a, int b){
  int s = __popc((a>>1)&b) + __popc((a>>2)&b) + __popc((a>>3)&b) + __popc((a>>4)&b) + ((a&b)>>4);
  return s & 1;
}

constexpr u32 sgn_mask(int m){
  u32 r = 0;
  for (int n=0;n<32;n++){
    int s = __builtin_popcount((m>>1)&n) + __builtin_popcount((m>>2)&n)
          + __builtin_popcount((m>>3)&n) + __builtin_popcount((m>>4)&n) + ((m&n)>>4);
    r |= (u32)(s&1) << n;
  }
  return r;
}
__device__ __constant__ u32 SGNC[32] = {
  sgn_mask(0), sgn_mask(1), sgn_mask(2), sgn_mask(3), sgn_mask(4), sgn_mask(5), sgn_mask(6), sgn_mask(7),
  sgn_mask(8), sgn_mask(9), sgn_mask(10),sgn_mask(11),sgn_mask(12),sgn_mask(13),sgn_mask(14),sgn_mask(15),
  sgn_mask(16),sgn_mask(17),sgn_mask(18),sgn_mask(19),sgn_mask(20),sgn_mask(21),sgn_mask(22),sgn_mask(23),
  sgn_mask(24),sgn_mask(25),sgn_mask(26),sgn_mask(27),sgn_mask(28),sgn_mask(29),sgn_mask(30),sgn_mask(31)};

DEVINL void gload_lds16(const void* g, void* l){
  __builtin_amdgcn_global_load_lds(
    (const __attribute__((address_space(1))) void*)g,
    (__attribute__((address_space(3))) void*)l, 16, 0, 0);
}

// ---------------- transpose x: [bs][i=256][n=32] f32 -> xt [bs*32+n][i] bf16 -----
__global__ __launch_bounds__(256) void k_tr_x(const float* __restrict__ x, u16* __restrict__ xt){
  __shared__ float tile[256][33];
  const int bs = blockIdx.x, t = threadIdx.x;
  const float* xp = x + (size_t)bs*8192 + t*32;
  #pragma unroll
  for (int n=0;n<32;n+=4){
    float4 v = *(const float4*)(xp + n);
    tile[t][n]=v.x; tile[t][n+1]=v.y; tile[t][n+2]=v.z; tile[t][n+3]=v.w;
  }
  __syncthreads();
  const int n = t>>3, i0 = (t&7)*32;
  u16* dst = xt + ((size_t)bs*32 + n)*256 + i0;
  #pragma unroll
  for (int q=0;q<4;q++){
    u32 w0 = pack2(tile[i0+q*8+0][n], tile[i0+q*8+1][n]);
    u32 w1 = pack2(tile[i0+q*8+2][n], tile[i0+q*8+3][n]);
    u32 w2 = pack2(tile[i0+q*8+4][n], tile[i0+q*8+5][n]);
    u32 w3 = pack2(tile[i0+q*8+6][n], tile[i0+q*8+7][n]);
    *(uint4*)(dst + q*8) = make_uint4(w0,w1,w2,w3);
  }
}

// ---------------- transpose w into MFMA-fragment order -----------------------------
// wT3[wsel][m][q][o_blk][kk][lane][e]: lane = (o&15) + k8*16, i = q*64+kk*32+k8*8+e
__global__ __launch_bounds__(256) void k_tr_w(const float* __restrict__ wq, const float* __restrict__ wk,
                                              const float* __restrict__ wv, const float* __restrict__ wo,
                                              u16* __restrict__ wT3){
  __shared__ float tile[256][33];
  const int bid = blockIdx.x, t = threadIdx.x;
  const int wsel = bid>>8, o = bid&255;
  const float* w = wsel==0?wq: wsel==1?wk: wsel==2?wv: wo;
  const float* wp = w + ((size_t)o*256 + t)*32;
  #pragma unroll
  for (int m=0;m<32;m+=4){
    float4 v = *(const float4*)(wp + m);
    tile[t][m]=v.x; tile[t][m+1]=v.y; tile[t][m+2]=v.z; tile[t][m+3]=v.w;
  }
  __syncthreads();
  const int m = t>>3, sub = t&7;
  const int q = sub>>1, kk = sub&1;
  const int c = o&15, obk = o>>4;
  const size_t base = (((((size_t)wsel*32 + m)*4 + q)*16 + obk)*2 + kk)*512;
  #pragma unroll
  for (int k8=0;k8<4;k8++){
    const int i0 = sub*32 + k8*8;
    u32 w0 = pack2(tile[i0+0][m], tile[i0+1][m]);
    u32 w1 = pack2(tile[i0+2][m], tile[i0+3][m]);
    u32 w2 = pack2(tile[i0+4][m], tile[i0+5][m]);
    u32 w3 = pack2(tile[i0+6][m], tile[i0+7][m]);
    *(uint4*)(wT3 + base + (size_t)(c + k8*16)*8) = make_uint4(w0,w1,w2,w3);
  }
}

// geo GEMM: out[bs,o,l] = sum_{m,i} xt[bs,l^m,i]*sign(m,l^m)*wT[m][o][i]
// 128x128 tile, 4 waves (2x2). A i-quarter LDS-resident in DUAL-SIGN form;
// per-m blade perm+sign is pure addressing. B streamed global->registers;
// IN-PLACE kk-split reload: Br[even] for m+1 loaded right after phase m's
// kk=0 MFMAs (covered by kk=1 compute), Br[odd] after kk=1. Zero extra VGPR.
template<int EPI>
__global__ __launch_bounds__(256) void k_geo_gemm(const u16* __restrict__ xt, const u16* __restrict__ wT3,
                                                  u16* __restrict__ qkv, float* __restrict__ dout,
                                                  float* __restrict__ Nq, float* __restrict__ Nk){
  constexpr int NT = (EPI==0)?6:2;
  constexpr int NWG = 256*NT;
  __shared__ __align__(16) u16 Apan[2*128*64];   // 32 KB: +A | -A
  const int wg = blockIdx.x;
  const int bid = (wg&7)*(NWG/8) + (wg>>3);      // bijective XCD chunking, tn-major
  const int tn = bid >> 8;
  const int tm = bid & 255;
  const int row0 = tm*128, col0 = tn*128;
  const int wsel = (EPI==0)? (col0>>8) : 3;
  const int o0   = (EPI==0)? (col0&255) : col0;
  const u16* Wp = wT3 + (size_t)wsel*2097152;    // panel base (u16)
  const int t = threadIdx.x, lane = t&63, wid = t>>6;
  const int wm = wid>>1, wn = wid&1, lo = lane&15, hi = lane>>4;

  // A base byte-offsets (m=0) and per-lane sign words
  int baseA[4][2]; u32 sgnw[4];
  #pragma unroll
  for (int f=0; f<4; ++f){
    const int ra = wm*64 + f*16 + lo;
    #pragma unroll
    for (int kk=0; kk<2; ++kk)
      baseA[f][kk] = ra*128 + (((kk*4+hi) ^ (lo&7))*16);
    const int rl = ra & 31;
    u32 sw = 0;
    for (int m=0;m<32;m++) sw |= ((SGNC[m] >> ((rl^m)&31)) & 1u) << m;
    sgnw[f] = sw;
  }
  // B fragment offsets (u16 units) within a (m,q) super-block
  int boff[4][2];
  #pragma unroll
  for (int fn=0; fn<4; ++fn){
    const int ob = (o0>>4) + wn*4 + fn;
    #pragma unroll
    for (int kk=0; kk<2; ++kk)
      boff[fn][kk] = (ob*2+kk)*512 + lane*8;
  }

  f32x4 acc[4][4];
  #pragma unroll
  for(int a=0;a<4;a++){
    #pragma unroll
    for(int b=0;b<4;b++){ acc[a][b] = (f32x4){0.f,0.f,0.f,0.f}; }
  }
  const char* Ab = (const char*)Apan;

  for (int q=0; q<4; ++q){
    __syncthreads();                 // previous quarter fully consumed
    #pragma unroll
    for (int c=0;c<4;c++){
      const int base = (wid*4+c)*64;
      const int idx = base + lane;
      const int rr = idx>>3, g = idx&7;
      gload_lds16(xt + (size_t)(row0+rr)*256 + q*64 + ((g^(rr&7))*8), Apan + base*8);
    }
    __syncthreads();                 // drain: +A quarter visible
    // build negated copy at +16KB (LDS->LDS, sign-bit XOR)
    #pragma unroll
    for (int c=0;c<4;c++){
      const int idx = c*256 + t;
      uint4 v = *(const uint4*)(Apan + idx*8);
      v.x^=0x80008000u; v.y^=0x80008000u; v.z^=0x80008000u; v.w^=0x80008000u;
      *(uint4*)(Apan + 8192 + idx*8) = v;
    }
    __syncthreads();                 // -A visible
    const u16* Wq = Wp + (size_t)q*16384;
    uint4 Br[8];
    #pragma unroll
    for (int fn=0; fn<4; ++fn){
      Br[fn*2+0] = *(const uint4*)(Wq + boff[fn][0]);
      Br[fn*2+1] = *(const uint4*)(Wq + boff[fn][1]);
    }
    for (int m=0; m<32; ++m){
      const int dlt = (m<<7) | ((m&7)<<4);
      const u16* Wn = Wq + (size_t)((m<31)? (m+1) : 31)*65536;
      // ---- kk=0: A frags + 16 MFMA on Br[even] ----
      bf16x8 af0[4];
      #pragma unroll
      for (int f=0; f<4; ++f){
        const int soff = (int)((sgnw[f] >> m) & 1u) << 14;
        af0[f] = *(const bf16x8*)(Ab + ((baseA[f][0] ^ dlt) | soff));
      }
      __builtin_amdgcn_s_setprio(1);
      #pragma unroll
      for (int fm=0;fm<4;fm++){
        #pragma unroll
        for (int fn=0;fn<4;fn++)
          acc[fm][fn] = __builtin_amdgcn_mfma_f32_16x16x32_bf16(
              af0[fm], *(const bf16x8*)&Br[fn*2+0], acc[fm][fn], 0,0,0);
      }
      __builtin_amdgcn_s_setprio(0);
      // reload even half for m+1 (covered by kk=1 compute)
      #pragma unroll
      for (int fn=0; fn<4; ++fn)
        Br[fn*2+0] = *(const uint4*)(Wn + boff[fn][0]);
      // ---- kk=1: A frags + 16 MFMA on Br[odd] ----
      bf16x8 af1[4];
      #pragma unroll
      for (int f=0; f<4; ++f){
        const int soff = (int)((sgnw[f] >> m) & 1u) << 14;
        af1[f] = *(const bf16x8*)(Ab + ((baseA[f][1] ^ dlt) | soff));
      }
      __builtin_amdgcn_s_setprio(1);
      #pragma unroll
      for (int fm=0;fm<4;fm++){
        #pragma unroll
        for (int fn=0;fn<4;fn++)
          acc[fm][fn] = __builtin_amdgcn_mfma_f32_16x16x32_bf16(
              af1[fm], *(const bf16x8*)&Br[fn*2+1], acc[fm][fn], 0,0,0);
      }
      __builtin_amdgcn_s_setprio(0);
      // reload odd half for m+1 (covered by next phase's A reads + kk=0)
      #pragma unroll
      for (int fn=0; fn<4; ++fn)
        Br[fn*2+1] = *(const uint4*)(Wn + boff[fn][1]);
    }
  }

  // epilogue: normalize each multivector; EPI==0 also emits fused Nq/Nk
  float hacc[2][2] = {{0.f,0.f},{0.f,0.f}};
  #pragma unroll
  for (int fn=0; fn<4; ++fn){
    const int c = col0 + wn*64 + fn*16 + lo;
    float s0=0.f, s1=0.f;
    #pragma unroll
    for (int r=0;r<4;r++){
      s0 += acc[0][fn][r]*acc[0][fn][r] + acc[1][fn][r]*acc[1][fn][r];
      s1 += acc[2][fn][r]*acc[2][fn][r] + acc[3][fn][r]*acc[3][fn][r];
    }
    s0 += __shfl_xor(s0,16); s0 += __shfl_xor(s0,32);
    s1 += __shfl_xor(s1,16); s1 += __shfl_xor(s1,32);
    if constexpr (EPI==0){
      hacc[fn>>1][0] += s0/(s0+1e-6f);
      hacc[fn>>1][1] += s1/(s1+1e-6f);
    }
    const float r0 = rsqrtf(s0+1e-6f), r1 = rsqrtf(s1+1e-6f);
    #pragma unroll
    for (int fm=0;fm<4;fm++){
      const float rs = (fm<2)? r0 : r1;
      const int bsg = (row0>>5) + wm*2 + (fm>>1);
      const int l0 = (fm&1)*16 + hi*4;
      float v0 = acc[fm][fn][0]*rs, v1 = acc[fm][fn][1]*rs, v2 = acc[fm][fn][2]*rs, v3 = acc[fm][fn][3]*rs;
      if constexpr (EPI==0){
        if (c < 256){ // fold SIG_DIAG into q
          if (sign_neg(l0+0,l0+0)) v0=-v0;
          if (sign_neg(l0+1,l0+1)) v1=-v1;
          if (sign_neg(l0+2,l0+2)) v2=-v2;
          if (sign_neg(l0+3,l0+3)) v3=-v3;
        }
        u16* dst = qkv + ((size_t)bsg*768 + c)*32 + l0;
        *(uint2*)dst = make_uint2(pack2(v0,v1), pack2(v2,v3));
      } else {
        float* dst = dout + ((size_t)bsg*256 + c)*32 + l0;
        *(float4*)dst = make_float4(v0,v1,v2,v3);
      }
    }
  }
  if constexpr (EPI==0){
    if (tn < 4){
      #pragma unroll
      for (int hs=0; hs<2; ++hs){
        #pragma unroll
        for (int p=0; p<2; ++p){
          float v = hacc[hs][p];
          v += __shfl_xor(v,1); v += __shfl_xor(v,2);
          v += __shfl_xor(v,4); v += __shfl_xor(v,8);
          hacc[hs][p] = v;
        }
      }
      if (lo==0 && hi==0){
        const int hb = ((col0&255)>>5) + wn*2;
        float* nd = (tn<2)? Nq : Nk;
        #pragma unroll
        for (int hs=0; hs<2; ++hs){
          #pragma unroll
          for (int p=0; p<2; ++p){
            const int bsf = (row0>>5) + wm*2 + p;
            const int b = bsf>>9, s = bsf&511;
            nd[((size_t)(b*8 + hb+hs))*512 + s] = hacc[hs][p];
          }
        }
      }
    }
  }
}

// ---------------- shared 128x128 MFMA tile engine (linear-row operands) -----------
DEVINL void mm_steps(const u16* Abase, int Astride, const u16* Bbase, int Bstride, int ksteps,
                     u16* Al, u16* Bl, f32x4 (&acc)[4][4], int lane, int wid){
  const int wm = wid>>1, wn = wid&1, lo = lane&15, hi = lane>>4;
  for (int s=0; s<ksteps; ++s){
    const int k0 = s*64;
    #pragma unroll
    for (int c=0;c<4;c++){
      const int gb = (wid*4+c)*64;
      const int idx = gb + lane;
      const int r = idx>>3, j = idx&7;
      const int sw = ((j^(r&7))*8);
      gload_lds16(Abase + (size_t)r*Astride + k0 + sw, Al + gb*8);
      gload_lds16(Bbase + (size_t)r*Bstride + k0 + sw, Bl + gb*8);
    }
    __syncthreads();
    #pragma unroll
    for (int kk=0; kk<2; ++kk){
      bf16x8 af[4], bfr[4];
      #pragma unroll
      for (int f=0;f<4;f++){
        const int ra = wm*64 + f*16 + lo;
        const int jc = kk*4 + hi;
        af[f] = *(const bf16x8*)(Al + ra*64 + ((jc^(ra&7))*8));
        const int rb = wn*64 + f*16 + lo;
        bfr[f] = *(const bf16x8*)(Bl + rb*64 + ((jc^(rb&7))*8));
      }
      #pragma unroll
      for (int fm=0;fm<4;fm++){
        #pragma unroll
        for (int fn=0;fn<4;fn++)
          acc[fm][fn] = __builtin_amdgcn_mfma_f32_16x16x32_bf16(af[fm], bfr[fn], acc[fm][fn], 0,0,0);
      }
    }
    __syncthreads();
  }
}

// ---------------- score: ss + gamma*bivector, write S1 f32 and S1T bf16 -----------
__global__ __launch_bounds__(256) void k_score(const u16* __restrict__ qkv, const float* __restrict__ Nq,
                                               const float* __restrict__ Nk, const float* __restrict__ gptr,
                                               float* __restrict__ S1, u16* __restrict__ S1T){
  __shared__ __align__(16) u16 Al[128*64];
  __shared__ __align__(16) u16 Bl[128*64];
  __shared__ __align__(16) u16 Tl[128*136];
  const int wg = blockIdx.x;
  const int bid = (wg&7)*32 + (wg>>3);
  const int bh = bid>>4, ti=(bid>>2)&3, tj=bid&3;
  const int b = bh>>3, h = bh&7;
  const int i0=ti*128, j0=tj*128;
  const int t=threadIdx.x, lane=t&63, wid=t>>6;
  const int wm=wid>>1, wn=wid&1, lo=lane&15, hi=lane>>4;
  f32x4 acc[4][4];
  #pragma unroll
  for(int a=0;a<4;a++){
    #pragma unroll
    for(int c=0;c<4;c++){ acc[a][c] = (f32x4){0.f,0.f,0.f,0.f}; }
  }
  const u16* Abase = qkv + ((size_t)(b*512+i0))*24576 + h*1024;
  const u16* Bbase = qkv + ((size_t)(b*512+j0))*24576 + 8192 + h*1024;
  mm_steps(Abase, 24576, Bbase, 24576, 16, Al, Bl, acc, lane, wid);
  const float gamma = *gptr;
  const float rhd = 0.17677669529663687f; // 1/sqrt(32)
  float nkv[4];
  #pragma unroll
  for (int fn=0;fn<4;fn++) nkv[fn] = Nk[bh*512 + j0 + wn*64 + fn*16 + lo];
  #pragma unroll
  for (int fm=0;fm<4;fm++){
    #pragma unroll
    for (int r=0;r<4;r++){
      const int iL = wm*64 + fm*16 + hi*4 + r;
      const float nq = Nq[bh*512 + i0 + iL];
      #pragma unroll
      for (int fn=0;fn<4;fn++){
        const int jL = wn*64 + fn*16 + lo;
        const float ss = acc[fm][fn][r];
        const float biv = sqrtf(fmaxf(nq*nkv[fn] - ss*ss, 0.f) + 1e-6f);
        const float sc = (ss + gamma*biv)*rhd;
        S1[((size_t)bh*512 + i0 + iL)*512 + j0 + jL] = sc;
        Tl[jL*136 + iL] = f2bf(sc);
      }
    }
  }
  __syncthreads();
  const int jj = t>>1, half = t&1;
  u16* dst = S1T + ((size_t)bh*512 + (j0+jj))*512 + i0 + half*64;
  #pragma unroll
  for (int q=0;q<8;q++)
    *(uint4*)(dst + q*8) = *(const uint4*)(Tl + jj*136 + half*64 + q*8);
}

// ---------------- row softmax, wave-per-row (optionally masked) -------------------
__global__ __launch_bounds__(256) void k_softmax(const float* __restrict__ S, const int* __restrict__ mask,
                                                 u16* __restrict__ P, int masked){
  const int t = threadIdx.x, lane = t&63, wid = t>>6;
  const int row = blockIdx.x*4 + wid;   // bh*512 + i
  const int b = row>>12;
  const float* sp = S + (size_t)row*512;
  float4 a = *(const float4*)(sp + lane*4);
  float4 c = *(const float4*)(sp + 256 + lane*4);
  if (masked){
    const int* mp = mask + b*512;
    int4 ma = *(const int4*)(mp + lane*4);
    int4 mc = *(const int4*)(mp + 256 + lane*4);
    if (ma.x==0) a.x=-1e9f; if (ma.y==0) a.y=-1e9f; if (ma.z==0) a.z=-1e9f; if (ma.w==0) a.w=-1e9f;
    if (mc.x==0) c.x=-1e9f; if (mc.y==0) c.y=-1e9f; if (mc.z==0) c.z=-1e9f; if (mc.w==0) c.w=-1e9f;
  }
  float mx = fmaxf(fmaxf(fmaxf(a.x,a.y),fmaxf(a.z,a.w)), fmaxf(fmaxf(c.x,c.y),fmaxf(c.z,c.w)));
  #pragma unroll
  for (int o=1;o<64;o<<=1) mx = fmaxf(mx, __shfl_xor(mx,o));
  const float e0=__expf(a.x-mx), e1=__expf(a.y-mx), e2=__expf(a.z-mx), e3=__expf(a.w-mx);
  const float e4=__expf(c.x-mx), e5=__expf(c.y-mx), e6=__expf(c.z-mx), e7=__expf(c.w-mx);
  float sm = (e0+e1)+(e2+e3)+(e4+e5)+(e6+e7);
  #pragma unroll
  for (int o=1;o<64;o<<=1) sm += __shfl_xor(sm,o);
  const float inv = 1.f/sm;
  u16* pp = P + (size_t)row*512;
  *(uint2*)(pp + lane*4)       = make_uint2(pack2(e0*inv,e1*inv), pack2(e2*inv,e3*inv));
  *(uint2*)(pp + 256 + lane*4) = make_uint2(pack2(e4*inv,e5*inv), pack2(e6*inv,e7*inv));
}

// ---------------- triangle update: S1 += 0.1 * P1 @ S1b (in place, f32) ----------
__global__ __launch_bounds__(256) void k_tri(const u16* __restrict__ P1, const u16* __restrict__ S1T,
                                             float* __restrict__ S1){
  __shared__ __align__(16) u16 Al[128*64];
  __shared__ __align__(16) u16 Bl[128*64];
  const int wg = blockIdx.x;
  const int bid = (wg&7)*32 + (wg>>3);
  const int bh = bid>>4, ti=(bid>>2)&3, tj=bid&3;
  const int i0=ti*128, j0=tj*128;
  const int t=threadIdx.x, lane=t&63, wid=t>>6;
  const int wm=wid>>1, wn=wid&1, lo=lane&15, hi=lane>>4;
  f32x4 acc[4][4];
  #pragma unroll
  for(int a=0;a<4;a++){
    #pragma unroll
    for(int c=0;c<4;c++){ acc[a][c] = (f32x4){0.f,0.f,0.f,0.f}; }
  }
  const u16* Abase = P1  + ((size_t)bh*512 + i0)*512;
  const u16* Bbase = S1T + ((size_t)bh*512 + j0)*512;
  mm_steps(Abase, 512, Bbase, 512, 8, Al, Bl, acc, lane, wid);
  #pragma unroll
  for (int fm=0;fm<4;fm++){
    #pragma unroll
    for (int r=0;r<4;r++){
      const int iL = wm*64 + fm*16 + hi*4 + r;
      #pragma unroll
      for (int fn=0;fn<4;fn++){
        const int jL = wn*64 + fn*16 + lo;
        const size_t idx = ((size_t)bh*512 + i0 + iL)*512 + j0 + jL;
        S1[idx] = S1[idx] + 0.1f*acc[fm][fn][r];
      }
    }
  }
}

// ---------------- transpose V to VT[bh][d][s] ------------------------------------
__global__ __launch_bounds__(256) void k_tr_v(const u16* __restrict__ qkv, u16* __restrict__ VT){
  __shared__ u16 tile[128*129];
  const int bid=blockIdx.x;
  const int bh = bid>>5, dch=(bid>>2)&7, sch=bid&3;
  const int b=bh>>3, h=bh&7;
  const int d0=dch*128, s0=sch*128;
  const int t=threadIdx.x;
  {
    const int r=t>>1, half=t&1;
    const u16* src = qkv + ((size_t)(b*512+s0+r))*24576 + 16384 + h*1024 + d0 + half*64;
    #pragma unroll
    for (int q=0;q<8;q++){
      uint4 v = *(const uint4*)(src + q*8);
      u16* dp = tile + r*129 + half*64 + q*8;
      dp[0]=(u16)(v.x&0xffffu); dp[1]=(u16)(v.x>>16); dp[2]=(u16)(v.y&0xffffu); dp[3]=(u16)(v.y>>16);
      dp[4]=(u16)(v.z&0xffffu); dp[5]=(u16)(v.z>>16); dp[6]=(u16)(v.w&0xffffu); dp[7]=(u16)(v.w>>16);
    }
  }
  __syncthreads();
  {
    const int rr=t>>1, half=t&1;
    u16* dst = VT + ((size_t)bh*1024 + d0+rr)*512 + s0 + half*64;
    #pragma unroll
    for (int q=0;q<4;q++){
      u32 w[8];
      #pragma unroll
      for (int e=0;e<8;e++){
        const int s = half*64 + q*16 + e*2;
        w[e] = (u32)tile[s*129+rr] | ((u32)tile[(s+1)*129+rr]<<16);
      }
      *(uint4*)(dst + q*16)     = make_uint4(w[0],w[1],w[2],w[3]);
      *(uint4*)(dst + q*16 + 8) = make_uint4(w[4],w[5],w[6],w[7]);
    }
  }
}

// ---------------- PV: out = P2 @ V, write transposed xt2[bs*32+l][e] bf16 --------
__global__ __launch_bounds__(256) void k_pv(const u16* __restrict__ P2, const u16* __restrict__ VT,
                                            u16* __restrict__ xt2){
  __shared__ __align__(16) u16 Al[128*64];
  __shared__ __align__(16) u16 Bl[128*64];
  __shared__ __align__(16) u16 Tl[128*136];
  const int wg = blockIdx.x;
  const int bid = (wg&7)*64 + (wg>>3);
  const int bh = bid>>5, ti=(bid>>3)&3, td=bid&7;
  const int b=bh>>3, h=bh&7;
  const int i0=ti*128, d0=td*128;
  const int t=threadIdx.x, lane=t&63, wid=t>>6;
  const int wm=wid>>1, wn=wid&1, lo=lane&15, hi=lane>>4;
  f32x4 acc[4][4];
  #pragma unroll
  for(int a=0;a<4;a++){
    #pragma unroll
    for(int c=0;c<4;c++){ acc[a][c] = (f32x4){0.f,0.f,0.f,0.f}; }
  }
  const u16* Abase = P2 + ((size_t)bh*512 + i0)*512;
  const u16* Bbase = VT + ((size_t)bh*1024 + d0)*512;
  mm_steps(Abase, 512, Bbase, 512, 8, Al, Bl, acc, lane, wid);
  #pragma unroll
  for (int fm=0;fm<4;fm++){
    #pragma unroll
    for (int r=0;r<4;r++){
      const int sL = wm*64 + fm*16 + hi*4 + r;
      #pragma unroll
      for (int fn=0;fn<4;fn++){
        const int dL = wn*64 + fn*16 + lo;
        Tl[sL*136 + dL] = f2bf(acc[fm][fn][r]);
      }
    }
  }
  __syncthreads();
  const int hd0 = td*4;
  #pragma unroll
  for (int u=0;u<16;u++){
    const int seg = t + u*256;
    const int sL = seg>>5, l = seg&31;
    const u16* tp = Tl + sL*136 + l;
    u32 w0 = (u32)tp[0]  | ((u32)tp[32]<<16);
    u32 w1 = (u32)tp[64] | ((u32)tp[96]<<16);
    u16* dst = xt2 + ((size_t)((b*512 + i0 + sL)*32 + l))*256 + h*32 + hd0;
    *(uint2*)dst = make_uint2(w0,w1);
  }
}

extern "C" void kernel_launch(void* const* d_in, const int* in_sizes, int n_in,
                              void* d_out, int out_size, void* d_ws, size_t ws_size,
                              hipStream_t stream) {
  const float* x  = (const float*)d_in[0];
  const float* wq = (const float*)d_in[1];
  const float* wk = (const float*)d_in[2];
  const float* wv = (const float*)d_in[3];
  const float* wo = (const float*)d_in[4];
  const float* gamma = (const float*)d_in[5];
  const int*   mask  = (const int*)d_in[6];
  float* out = (float*)d_out;

  char* ws = (char*)d_ws;
  size_t off = 0;
  auto alloc = [&](size_t n){ char* p = ws + off; off += (n + 255) & ~(size_t)255; return p; };
  u16*  xt  = (u16*) alloc(16777216);   // [32768][256] bf16
  u16*  wT3 = (u16*) alloc(16777216);   // [4][32][4][16][2][64][8] bf16 fragment-order
  u16*  qkv = (u16*) alloc(50331648);   // [1024][768][32] bf16
  float* Nq = (float*)alloc(32768);
  float* Nk = (float*)alloc(32768);
  float* S1 = (float*)alloc(16777216);  // [16][512][512] f32
  u16*  S1T = (u16*) alloc(8388608);    // [16][512][512] bf16 (transposed)
  u16*  P2  = (u16*) alloc(8388608);
  u16*  VT  = (u16*) alloc(16777216);   // [16][1024][512] bf16
  u16*  P1  = xt;                       // alias: xt dead after gemm<0>; P1 dead before k_pv writes xt2
  u16*  xt2 = xt;                       // alias: reuse xt region for attention output

  k_tr_x<<<1024, 256, 0, stream>>>(x, xt);
  k_tr_w<<<1024, 256, 0, stream>>>(wq, wk, wv, wo, wT3);
  k_geo_gemm<0><<<1536, 256, 0, stream>>>(xt, wT3, qkv, nullptr, Nq, Nk);
  k_score<<<256, 256, 0, stream>>>(qkv, Nq, Nk, gamma, S1, S1T);
  k_softmax<<<2048, 256, 0, stream>>>(S1, mask, P1, 0);
  k_tri<<<256, 256, 0, stream>>>(P1, S1T, S1);
  k_softmax<<<2048, 256, 0, stream>>>(S1, mask, P2, 1);
  k_tr_v<<<512, 256, 0, stream>>>(qkv, VT);
  k_pv<<<512, 256, 0, stream>>>(P2, VT, xt2);
  k_geo_gemm<1><<<512, 256, 0, stream>>>(xt2, wT3, nullptr, out, nullptr, nullptr);
}

// Round 13
// 309.408 us; speedup vs baseline: 2.3471x; 1.7473x over previous
//
#include <hip/hip_runtime.h>
#include <stdint.h>

typedef unsigned short u16;
typedef unsigned int u32;
typedef __attribute__((ext_vector_type(8))) __bf16 bf16x8;
typedef __attribute__((ext_vector_type(4))) float f32x4;

#define DEVINL __device__ __forceinline__

DEVINL float bf2f(u16 u){ union{u32 i; float f;} c; c.i = ((u32)u)<<16; return c.f; }
DEVINL u16 f2bf(float f){ union{float f; u32 i;} c; c.f=f; u32 u=c.i; return (u16)((u + 0x7fffu + ((u>>16)&1u))>>16); }
DEVINL u32 pack2(float a, float b){ return (u32)f2bf(a) | ((u32)f2bf(b)<<16); }

// parity of sign(e_a * e_b) in Cl(4,1) (used only for SIG_DIAG fold: sign of e_l^2)
DEVINL int sign_neg(int a, int b){
  int s = __popc((a>>1)&b) + __popc((a>>2)&b) + __popc((a>>3)&b) + __popc((a>>4)&b) + ((a&b)>>4);
  return s & 1;
}

// ---- Cl(4,1) -> M4(C) rep: blade I -> generalized permutation matrix:
// row r has single nonzero i^ph[I][r] at column col[I][r].
struct GTab { int col[32][4]; int ph[32][4]; };
constexpr GTab make_gtab(){
  GTab g{};
  int gc[5][4] = {}; int gp[5][4] = {};
  for (int r=0;r<4;r++){
    const int a=(r>>1)&1, b=r&1;
    gc[0][r]=r^2; gp[0][r]=0;                        // e0 = s1 x I
    gc[1][r]=r^2; gp[1][r]= a?1:3;                   // e1 = s2 x I
    gc[2][r]=r^1; gp[2][r]= a?2:0;                   // e2 = s3 x s1
    gc[3][r]=r^1; gp[3][r]=((a?2:0)+(b?1:3))&3;      // e3 = s3 x s2
    gc[4][r]=r;   gp[4][r]=(3+(a?2:0)+(b?2:0))&3;    // e4 = -i s3 x s3 (e4^2=-I)
  }
  for (int I=0;I<32;I++){
    for (int r=0;r<4;r++){ g.col[I][r]=r; g.ph[I][r]=0; }
    for (int bit=0;bit<5;bit++) if ((I>>bit)&1){
      for (int r=0;r<4;r++){
        const int c = g.col[I][r];
        g.ph[I][r]  = (g.ph[I][r] + gp[bit][c]) & 3;
        g.col[I][r] = gc[bit][c];
      }
    }
  }
  return g;
}
constexpr GTab GT = make_gtab();

// mv (32 reals) -> 4x4 complex matrix
DEVINL void mv2mat(const float (&x)[32], float (&Mre)[4][4], float (&Mim)[4][4]){
  #pragma unroll
  for (int r=0;r<4;r++)
    #pragma unroll
    for (int c=0;c<4;c++){ Mre[r][c]=0.f; Mim[r][c]=0.f; }
  #pragma unroll
  for (int l=0;l<32;l++){
    #pragma unroll
    for (int r=0;r<4;r++){
      constexpr const GTab& G = GT;
      const int c = G.col[l][r], p = G.ph[l][r];
      if (p==0) Mre[r][c] += x[l];
      else if (p==1) Mim[r][c] += x[l];
      else if (p==2) Mre[r][c] -= x[l];
      else Mim[r][c] -= x[l];
    }
  }
}

// v[c][r8] (r8<4: Re M[r8][c], r8>=4: Im M[r8-4][c]) -> mv
DEVINL void mat2mv(const float (&v)[4][8], float (&x)[32]){
  #pragma unroll
  for (int l=0;l<32;l++){
    float s = 0.f;
    #pragma unroll
    for (int r=0;r<4;r++){
      constexpr const GTab& G = GT;
      const int c = G.col[l][r], p = G.ph[l][r];
      if (p==0) s += v[c][r];
      else if (p==1) s += v[c][4+r];
      else if (p==2) s -= v[c][r];
      else s -= v[c][4+r];
    }
    x[l] = 0.25f*s;
  }
}

DEVINL void gload_lds16(const void* g, void* l){
  __builtin_amdgcn_global_load_lds(
    (const __attribute__((address_space(1))) void*)g,
    (__attribute__((address_space(3))) void*)l, 16, 0, 0);
}

// ---------------- x -> A-matrix: Am[(bs*4+c)][i*8+kk8] bf16 ----------------------
__global__ __launch_bounds__(256) void k_v2m(const float* __restrict__ x, u16* __restrict__ Am){
  const int bs = blockIdx.x, i = threadIdx.x;
  const float* xp = x + ((size_t)bs*256 + i)*32;
  float xv[32];
  #pragma unroll
  for (int q=0;q<8;q++){
    float4 v = *(const float4*)(xp + q*4);
    xv[q*4+0]=v.x; xv[q*4+1]=v.y; xv[q*4+2]=v.z; xv[q*4+3]=v.w;
  }
  float Mre[4][4], Mim[4][4];
  mv2mat(xv, Mre, Mim);
  #pragma unroll
  for (int c=0;c<4;c++){
    u32 w0 = pack2(Mre[0][c], Mre[1][c]);
    u32 w1 = pack2(Mre[2][c], Mre[3][c]);
    u32 w2 = pack2(Mim[0][c], Mim[1][c]);
    u32 w3 = pack2(Mim[2][c], Mim[3][c]);
    *(uint4*)(Am + ((size_t)(bs*4+c))*2048 + i*8) = make_uint4(w0,w1,w2,w3);
  }
}

// ---------------- w -> B fragment-order --------------------------------------------
// Bfo[sel][kq(32)][nblk(128)][kk(2)][lane(64)][e(8)]: value B[k][(o,r8)] = W8[o,i][r8][kk8]
// where n = o*8+r8 = nblk*16 + (lane&15), k = i*8+kk8 = kq*64 + kk*32 + (lane>>4)*8 + e
__global__ __launch_bounds__(256) void k_w2m(const float* __restrict__ wq, const float* __restrict__ wk,
                                             const float* __restrict__ wv, const float* __restrict__ wo,
                                             u16* __restrict__ Bfo){
  const int bid = blockIdx.x, i = threadIdx.x;
  const int wsel = bid>>8, o = bid&255;
  const float* w = wsel==0?wq: wsel==1?wk: wsel==2?wv: wo;
  const float* wp = w + ((size_t)o*256 + i)*32;
  float wv32[32];
  #pragma unroll
  for (int q=0;q<8;q++){
    float4 v = *(const float4*)(wp + q*4);
    wv32[q*4+0]=v.x; wv32[q*4+1]=v.y; wv32[q*4+2]=v.z; wv32[q*4+3]=v.w;
  }
  float Wre[4][4], Wim[4][4];
  mv2mat(wv32, Wre, Wim);
  u16* base = Bfo + (size_t)wsel*4194304 + (size_t)(i>>3)*131072 + (o>>1)*1024
            + ((i>>2)&1)*512;
  const int lanebase = (o&1)*8 + (i&3)*16;
  #pragma unroll
  for (int r8=0;r8<8;r8++){
    float e0,e1,e2,e3,e4,e5,e6,e7;
    if (r8<4){
      e0=Wre[r8][0]; e1=Wre[r8][1]; e2=Wre[r8][2]; e3=Wre[r8][3];
      e4=-Wim[r8][0]; e5=-Wim[r8][1]; e6=-Wim[r8][2]; e7=-Wim[r8][3];
    } else {
      e0=Wim[r8-4][0]; e1=Wim[r8-4][1]; e2=Wim[r8-4][2]; e3=Wim[r8-4][3];
      e4=Wre[r8-4][0]; e5=Wre[r8-4][1]; e6=Wre[r8-4][2]; e7=Wre[r8-4][3];
    }
    *(uint4*)(base + (lanebase + r8)*8) =
      make_uint4(pack2(e0,e1), pack2(e2,e3), pack2(e4,e5), pack2(e6,e7));
  }
}

// ---------------- matrix-basis GEMM: C = Am x Bfo, fused m2v epilogue --------------
// M=4096 (bs,c), K=2048 (i,kk8), N = 6144 (qkv) or 2048 (wo). 128x128 tile, 4 waves.
template<int EPI>
__global__ __launch_bounds__(256) void k_mgemm(const u16* __restrict__ Am, const u16* __restrict__ Bfo,
                                               u16* __restrict__ qkv, float* __restrict__ dout,
                                               float* __restrict__ Nqp, float* __restrict__ Nkp){
  constexpr int NT = (EPI==0)?48:16;
  constexpr int NWG = 32*NT;
  __shared__ __align__(16) u16 SM[128*136];      // [0,8192): A stage; full: epilogue Cl
  const int wg = blockIdx.x;
  const int bid = (wg&7)*(NWG/8) + (wg>>3);      // bijective XCD chunking
  const int tn = bid>>5, tm = bid&31;            // tn-major: B panel per XCD
  const int row0 = tm*128, col0 = tn*128;
  const int sel   = (EPI==0)? (col0>>11) : 3;
  const int ncol0 = (EPI==0)? (col0&2047) : col0;
  const u16* Wsel = Bfo + (size_t)sel*4194304;
  const int t = threadIdx.x, lane = t&63, wid = t>>6;
  const int wm = wid>>1, wn = wid&1, lo = lane&15, hi = lane>>4;

  int boff[4][2];
  #pragma unroll
  for (int fn=0; fn<4; ++fn){
    const int nblk = (ncol0>>4) + wn*4 + fn;
    #pragma unroll
    for (int kk=0; kk<2; ++kk)
      boff[fn][kk] = (nblk*2+kk)*512 + lane*8;
  }

  f32x4 acc[4][4];
  #pragma unroll
  for(int a=0;a<4;a++){
    #pragma unroll
    for(int b=0;b<4;b++){ acc[a][b] = (f32x4){0.f,0.f,0.f,0.f}; }
  }

  for (int kq=0; kq<32; ++kq){
    __syncthreads();                       // prev A tile consumed
    // issue B fragment loads (drained together with A at next barrier)
    const u16* Wq = Wsel + (size_t)kq*131072;
    uint4 Br[8];
    #pragma unroll
    for (int fn=0; fn<4; ++fn){
      Br[fn*2+0] = *(const uint4*)(Wq + boff[fn][0]);
      Br[fn*2+1] = *(const uint4*)(Wq + boff[fn][1]);
    }
    // stage A tile 128x64
    #pragma unroll
    for (int c=0;c<4;c++){
      const int base = (wid*4+c)*64;
      const int idx = base + lane;
      const int rr = idx>>3, g = idx&7;
      gload_lds16(Am + (size_t)(row0+rr)*2048 + kq*64 + ((g^(rr&7))*8), SM + base*8);
    }
    __syncthreads();                       // vmcnt drain: A visible, B regs ready
    #pragma unroll
    for (int kk=0; kk<2; ++kk){
      bf16x8 af[4];
      #pragma unroll
      for (int f=0;f<4;f++){
        const int ra = wm*64 + f*16 + lo;
        const int jc = kk*4 + hi;
        af[f] = *(const bf16x8*)(SM + ra*64 + ((jc^(ra&7))*8));
      }
      __builtin_amdgcn_s_setprio(1);
      #pragma unroll
      for (int fm=0;fm<4;fm++){
        #pragma unroll
        for (int fn=0;fn<4;fn++)
          acc[fm][fn] = __builtin_amdgcn_mfma_f32_16x16x32_bf16(
              af[fm], *(const bf16x8*)&Br[fn*2+kk], acc[fm][fn], 0,0,0);
      }
      __builtin_amdgcn_s_setprio(0);
    }
  }

  // ---- epilogue: dump C tile to LDS, reassemble multivectors, m2v + normalize ----
  __syncthreads();
  #pragma unroll
  for (int fm=0;fm<4;fm++){
    #pragma unroll
    for (int r=0;r<4;r++){
      const int mL = wm*64 + fm*16 + hi*4 + r;
      #pragma unroll
      for (int fn=0;fn<4;fn++){
        const int nL = wn*64 + fn*16 + lo;
        SM[mL*136 + nL] = f2bf(acc[fm][fn][r]);
      }
    }
  }
  __syncthreads();
  const int bsL = t>>3, oLp = t&7;
  const int bs = (row0>>2) + bsL;
  const int o0w = ncol0>>3;
  float nsum = 0.f;
  #pragma unroll
  for (int u=0;u<2;u++){
    const int oL = oLp + u*8;
    float v[4][8];
    #pragma unroll
    for (int c=0;c<4;c++){
      uint4 q4 = *(const uint4*)(SM + (bsL*4+c)*136 + oL*8);
      v[c][0]=bf2f((u16)(q4.x&0xffffu)); v[c][1]=bf2f((u16)(q4.x>>16));
      v[c][2]=bf2f((u16)(q4.y&0xffffu)); v[c][3]=bf2f((u16)(q4.y>>16));
      v[c][4]=bf2f((u16)(q4.z&0xffffu)); v[c][5]=bf2f((u16)(q4.z>>16));
      v[c][6]=bf2f((u16)(q4.w&0xffffu)); v[c][7]=bf2f((u16)(q4.w>>16));
    }
    float xs[32];
    mat2mv(v, xs);
    float s = 0.f;
    #pragma unroll
    for (int l=0;l<32;l++) s += xs[l]*xs[l];
    const float rs = rsqrtf(s + 1e-6f);
    if constexpr (EPI==0){
      nsum += s/(s+1e-6f);
      if (sel == 0){
        #pragma unroll
        for (int l=0;l<32;l++) xs[l] = sign_neg(l,l)? -xs[l]*rs : xs[l]*rs;
      } else {
        #pragma unroll
        for (int l=0;l<32;l++) xs[l] *= rs;
      }
      u16* dst = qkv + ((size_t)bs*768 + sel*256 + o0w + oL)*32;
      #pragma unroll
      for (int q=0;q<4;q++)
        *(uint4*)(dst + q*8) = make_uint4(pack2(xs[q*8+0],xs[q*8+1]), pack2(xs[q*8+2],xs[q*8+3]),
                                          pack2(xs[q*8+4],xs[q*8+5]), pack2(xs[q*8+6],xs[q*8+7]));
    } else {
      float* dst = dout + ((size_t)bs*256 + o0w + oL)*32;
      #pragma unroll
      for (int q=0;q<8;q++)
        *(float4*)(dst + q*4) = make_float4(xs[q*4+0]*rs, xs[q*4+1]*rs, xs[q*4+2]*rs, xs[q*4+3]*rs);
    }
  }
  if constexpr (EPI==0){
    if (sel < 2){
      nsum += __shfl_xor(nsum,1); nsum += __shfl_xor(nsum,2); nsum += __shfl_xor(nsum,4);
      if ((t&7)==0){
        const int half = (o0w>>4)&1, h = o0w>>5;
        const int b = bs>>9, s_ = bs&511;
        float* nd = (sel==0)? Nqp : Nkp;
        nd[half*8192 + (b*8+h)*512 + s_] = nsum;
      }
    }
  }
}

// ---------------- shared 128x128 MFMA tile engine (linear-row operands) -----------
DEVINL void mm_steps(const u16* Abase, int Astride, const u16* Bbase, int Bstride, int ksteps,
                     u16* Al, u16* Bl, f32x4 (&acc)[4][4], int lane, int wid){
  const int wm = wid>>1, wn = wid&1, lo = lane&15, hi = lane>>4;
  for (int s=0; s<ksteps; ++s){
    const int k0 = s*64;
    #pragma unroll
    for (int c=0;c<4;c++){
      const int gb = (wid*4+c)*64;
      const int idx = gb + lane;
      const int r = idx>>3, j = idx&7;
      const int sw = ((j^(r&7))*8);
      gload_lds16(Abase + (size_t)r*Astride + k0 + sw, Al + gb*8);
      gload_lds16(Bbase + (size_t)r*Bstride + k0 + sw, Bl + gb*8);
    }
    __syncthreads();
    #pragma unroll
    for (int kk=0; kk<2; ++kk){
      bf16x8 af[4], bfr[4];
      #pragma unroll
      for (int f=0;f<4;f++){
        const int ra = wm*64 + f*16 + lo;
        const int jc = kk*4 + hi;
        af[f] = *(const bf16x8*)(Al + ra*64 + ((jc^(ra&7))*8));
        const int rb = wn*64 + f*16 + lo;
        bfr[f] = *(const bf16x8*)(Bl + rb*64 + ((jc^(rb&7))*8));
      }
      #pragma unroll
      for (int fm=0;fm<4;fm++){
        #pragma unroll
        for (int fn=0;fn<4;fn++)
          acc[fm][fn] = __builtin_amdgcn_mfma_f32_16x16x32_bf16(af[fm], bfr[fn], acc[fm][fn], 0,0,0);
      }
    }
    __syncthreads();
  }
}

// ---------------- score: ss + gamma*bivector, write S1 f32 and S1T bf16 -----------
__global__ __launch_bounds__(256) void k_score(const u16* __restrict__ qkv, const float* __restrict__ Nqp,
                                               const float* __restrict__ Nkp, const float* __restrict__ gptr,
                                               float* __restrict__ S1, u16* __restrict__ S1T){
  __shared__ __align__(16) u16 Al[128*64];
  __shared__ __align__(16) u16 Bl[128*64];
  __shared__ __align__(16) u16 Tl[128*136];
  const int wg = blockIdx.x;
  const int bid = (wg&7)*32 + (wg>>3);
  const int bh = bid>>4, ti=(bid>>2)&3, tj=bid&3;
  const int b = bh>>3, h = bh&7;
  const int i0=ti*128, j0=tj*128;
  const int t=threadIdx.x, lane=t&63, wid=t>>6;
  const int wm=wid>>1, wn=wid&1, lo=lane&15, hi=lane>>4;
  f32x4 acc[4][4];
  #pragma unroll
  for(int a=0;a<4;a++){
    #pragma unroll
    for(int c=0;c<4;c++){ acc[a][c] = (f32x4){0.f,0.f,0.f,0.f}; }
  }
  const u16* Abase = qkv + ((size_t)(b*512+i0))*24576 + h*1024;
  const u16* Bbase = qkv + ((size_t)(b*512+j0))*24576 + 8192 + h*1024;
  mm_steps(Abase, 24576, Bbase, 24576, 16, Al, Bl, acc, lane, wid);
  const float gamma = *gptr;
  const float rhd = 0.17677669529663687f; // 1/sqrt(32)
  float nkv[4];
  #pragma unroll
  for (int fn=0;fn<4;fn++){
    const int idx = bh*512 + j0 + wn*64 + fn*16 + lo;
    nkv[fn] = Nkp[idx] + Nkp[8192 + idx];
  }
  #pragma unroll
  for (int fm=0;fm<4;fm++){
    #pragma unroll
    for (int r=0;r<4;r++){
      const int iL = wm*64 + fm*16 + hi*4 + r;
      const int qidx = bh*512 + i0 + iL;
      const float nq = Nqp[qidx] + Nqp[8192 + qidx];
      #pragma unroll
      for (int fn=0;fn<4;fn++){
        const int jL = wn*64 + fn*16 + lo;
        const float ss = acc[fm][fn][r];
        const float biv = sqrtf(fmaxf(nq*nkv[fn] - ss*ss, 0.f) + 1e-6f);
        const float sc = (ss + gamma*biv)*rhd;
        S1[((size_t)bh*512 + i0 + iL)*512 + j0 + jL] = sc;
        Tl[jL*136 + iL] = f2bf(sc);
      }
    }
  }
  __syncthreads();
  const int jj = t>>1, half = t&1;
  u16* dst = S1T + ((size_t)bh*512 + (j0+jj))*512 + i0 + half*64;
  #pragma unroll
  for (int q=0;q<8;q++)
    *(uint4*)(dst + q*8) = *(const uint4*)(Tl + jj*136 + half*64 + q*8);
}

// ---------------- row softmax, wave-per-row (optionally masked) -------------------
__global__ __launch_bounds__(256) void k_softmax(const float* __restrict__ S, const int* __restrict__ mask,
                                                 u16* __restrict__ P, int masked){
  const int t = threadIdx.x, lane = t&63, wid = t>>6;
  const int row = blockIdx.x*4 + wid;   // bh*512 + i
  const int b = row>>12;
  const float* sp = S + (size_t)row*512;
  float4 a = *(const float4*)(sp + lane*4);
  float4 c = *(const float4*)(sp + 256 + lane*4);
  if (masked){
    const int* mp = mask + b*512;
    int4 ma = *(const int4*)(mp + lane*4);
    int4 mc = *(const int4*)(mp + 256 + lane*4);
    if (ma.x==0) a.x=-1e9f; if (ma.y==0) a.y=-1e9f; if (ma.z==0) a.z=-1e9f; if (ma.w==0) a.w=-1e9f;
    if (mc.x==0) c.x=-1e9f; if (mc.y==0) c.y=-1e9f; if (mc.z==0) c.z=-1e9f; if (mc.w==0) c.w=-1e9f;
  }
  float mx = fmaxf(fmaxf(fmaxf(a.x,a.y),fmaxf(a.z,a.w)), fmaxf(fmaxf(c.x,c.y),fmaxf(c.z,c.w)));
  #pragma unroll
  for (int o=1;o<64;o<<=1) mx = fmaxf(mx, __shfl_xor(mx,o));
  const float e0=__expf(a.x-mx), e1=__expf(a.y-mx), e2=__expf(a.z-mx), e3=__expf(a.w-mx);
  const float e4=__expf(c.x-mx), e5=__expf(c.y-mx), e6=__expf(c.z-mx), e7=__expf(c.w-mx);
  float sm = (e0+e1)+(e2+e3)+(e4+e5)+(e6+e7);
  #pragma unroll
  for (int o=1;o<64;o<<=1) sm += __shfl_xor(sm,o);
  const float inv = 1.f/sm;
  u16* pp = P + (size_t)row*512;
  *(uint2*)(pp + lane*4)       = make_uint2(pack2(e0*inv,e1*inv), pack2(e2*inv,e3*inv));
  *(uint2*)(pp + 256 + lane*4) = make_uint2(pack2(e4*inv,e5*inv), pack2(e6*inv,e7*inv));
}

// ---------------- triangle update: S1 += 0.1 * P1 @ S1b (in place, f32) ----------
__global__ __launch_bounds__(256) void k_tri(const u16* __restrict__ P1, const u16* __restrict__ S1T,
                                             float* __restrict__ S1){
  __shared__ __align__(16) u16 Al[128*64];
  __shared__ __align__(16) u16 Bl[128*64];
  const int wg = blockIdx.x;
  const int bid = (wg&7)*32 + (wg>>3);
  const int bh = bid>>4, ti=(bid>>2)&3, tj=bid&3;
  const int i0=ti*128, j0=tj*128;
  const int t=threadIdx.x, lane=t&63, wid=t>>6;
  const int wm=wid>>1, wn=wid&1, lo=lane&15, hi=lane>>4;
  f32x4 acc[4][4];
  #pragma unroll
  for(int a=0;a<4;a++){
    #pragma unroll
    for(int c=0;c<4;c++){ acc[a][c] = (f32x4){0.f,0.f,0.f,0.f}; }
  }
  const u16* Abase = P1  + ((size_t)bh*512 + i0)*512;
  const u16* Bbase = S1T + ((size_t)bh*512 + j0)*512;
  mm_steps(Abase, 512, Bbase, 512, 8, Al, Bl, acc, lane, wid);
  #pragma unroll
  for (int fm=0;fm<4;fm++){
    #pragma unroll
    for (int r=0;r<4;r++){
      const int iL = wm*64 + fm*16 + hi*4 + r;
      #pragma unroll
      for (int fn=0;fn<4;fn++){
        const int jL = wn*64 + fn*16 + lo;
        const size_t idx = ((size_t)bh*512 + i0 + iL)*512 + j0 + jL;
        S1[idx] = S1[idx] + 0.1f*acc[fm][fn][r];
      }
    }
  }
}

// ---------------- transpose V to VT[bh][d][s] ------------------------------------
__global__ __launch_bounds__(256) void k_tr_v(const u16* __restrict__ qkv, u16* __restrict__ VT){
  __shared__ u16 tile[128*129];
  const int bid=blockIdx.x;
  const int bh = bid>>5, dch=(bid>>2)&7, sch=bid&3;
  const int b=bh>>3, h=bh&7;
  const int d0=dch*128, s0=sch*128;
  const int t=threadIdx.x;
  {
    const int r=t>>1, half=t&1;
    const u16* src = qkv + ((size_t)(b*512+s0+r))*24576 + 16384 + h*1024 + d0 + half*64;
    #pragma unroll
    for (int q=0;q<8;q++){
      uint4 v = *(const uint4*)(src + q*8);
      u16* dp = tile + r*129 + half*64 + q*8;
      dp[0]=(u16)(v.x&0xffffu); dp[1]=(u16)(v.x>>16); dp[2]=(u16)(v.y&0xffffu); dp[3]=(u16)(v.y>>16);
      dp[4]=(u16)(v.z&0xffffu); dp[5]=(u16)(v.z>>16); dp[6]=(u16)(v.w&0xffffu); dp[7]=(u16)(v.w>>16);
    }
  }
  __syncthreads();
  {
    const int rr=t>>1, half=t&1;
    u16* dst = VT + ((size_t)bh*1024 + d0+rr)*512 + s0 + half*64;
    #pragma unroll
    for (int q=0;q<4;q++){
      u32 w[8];
      #pragma unroll
      for (int e=0;e<8;e++){
        const int s = half*64 + q*16 + e*2;
        w[e] = (u32)tile[s*129+rr] | ((u32)tile[(s+1)*129+rr]<<16);
      }
      *(uint4*)(dst + q*16)     = make_uint4(w[0],w[1],w[2],w[3]);
      *(uint4*)(dst + q*16 + 8) = make_uint4(w[4],w[5],w[6],w[7]);
    }
  }
}

// ---------------- PV: out = P2 @ V, epilogue writes mat-basis Amat2 ---------------
__global__ __launch_bounds__(256) void k_pv(const u16* __restrict__ P2, const u16* __restrict__ VT,
                                            u16* __restrict__ Am2){
  __shared__ __align__(16) u16 Al[128*64];
  __shared__ __align__(16) u16 Bl[128*64];
  __shared__ __align__(16) u16 Tl[128*136];
  const int wg = blockIdx.x;
  const int bid = (wg&7)*64 + (wg>>3);
  const int bh = bid>>5, ti=(bid>>3)&3, td=bid&7;
  const int b=bh>>3, h=bh&7;
  const int i0=ti*128, d0=td*128;
  const int t=threadIdx.x, lane=t&63, wid=t>>6;
  const int wm=wid>>1, wn=wid&1, lo=lane&15, hi=lane>>4;
  f32x4 acc[4][4];
  #pragma unroll
  for(int a=0;a<4;a++){
    #pragma unroll
    for(int c=0;c<4;c++){ acc[a][c] = (f32x4){0.f,0.f,0.f,0.f}; }
  }
  const u16* Abase = P2 + ((size_t)bh*512 + i0)*512;
  const u16* Bbase = VT + ((size_t)bh*1024 + d0)*512;
  mm_steps(Abase, 512, Bbase, 512, 8, Al, Bl, acc, lane, wid);
  #pragma unroll
  for (int fm=0;fm<4;fm++){
    #pragma unroll
    for (int r=0;r<4;r++){
      const int sL = wm*64 + fm*16 + hi*4 + r;
      #pragma unroll
      for (int fn=0;fn<4;fn++){
        const int dL = wn*64 + fn*16 + lo;
        Tl[sL*136 + dL] = f2bf(acc[fm][fn][r]);
      }
    }
  }
  __syncthreads();
  // reassemble multivectors (128 s x 4 hd) and write A-matrix rows for gemm<1>
  #pragma unroll
  for (int u=0;u<2;u++){
    const int idx = t + u*256;
    const int sL = idx>>2, hdL = idx&3;
    const u16* tp = Tl + sL*136 + hdL*32;
    float xv[32];
    #pragma unroll
    for (int q=0;q<4;q++){
      uint4 v = *(const uint4*)(tp + q*8);
      xv[q*8+0]=bf2f((u16)(v.x&0xffffu)); xv[q*8+1]=bf2f((u16)(v.x>>16));
      xv[q*8+2]=bf2f((u16)(v.y&0xffffu)); xv[q*8+3]=bf2f((u16)(v.y>>16));
      xv[q*8+4]=bf2f((u16)(v.z&0xffffu)); xv[q*8+5]=bf2f((u16)(v.z>>16));
      xv[q*8+6]=bf2f((u16)(v.w&0xffffu)); xv[q*8+7]=bf2f((u16)(v.w>>16));
    }
    float Mre[4][4], Mim[4][4];
    mv2mat(xv, Mre, Mim);
    const int e = h*32 + td*4 + hdL;
    const size_t mrow = ((size_t)(b*512 + i0 + sL))*4;
    #pragma unroll
    for (int c=0;c<4;c++){
      u32 w0 = pack2(Mre[0][c], Mre[1][c]);
      u32 w1 = pack2(Mre[2][c], Mre[3][c]);
      u32 w2 = pack2(Mim[0][c], Mim[1][c]);
      u32 w3 = pack2(Mim[2][c], Mim[3][c]);
      *(uint4*)(Am2 + (mrow + c)*2048 + e*8) = make_uint4(w0,w1,w2,w3);
    }
  }
}

extern "C" void kernel_launch(void* const* d_in, const int* in_sizes, int n_in,
                              void* d_out, int out_size, void* d_ws, size_t ws_size,
                              hipStream_t stream) {
  const float* x  = (const float*)d_in[0];
  const float* wq = (const float*)d_in[1];
  const float* wk = (const float*)d_in[2];
  const float* wv = (const float*)d_in[3];
  const float* wo = (const float*)d_in[4];
  const float* gamma = (const float*)d_in[5];
  const int*   mask  = (const int*)d_in[6];
  float* out = (float*)d_out;

  char* ws = (char*)d_ws;
  size_t off = 0;
  auto alloc = [&](size_t n){ char* p = ws + off; off += (n + 255) & ~(size_t)255; return p; };
  u16*  Am  = (u16*) alloc(16777216);   // [4096][2048] bf16 (later: P1 8MB, then Am2)
  u16*  Bfo = (u16*) alloc(33554432);   // [4][32][128][2][64][8] bf16
  u16*  qkv = (u16*) alloc(50331648);   // [1024][768][32] bf16
  float* Nqp = (float*)alloc(65536);    // [2][8192]
  float* Nkp = (float*)alloc(65536);
  float* S1 = (float*)alloc(16777216);  // [16][512][512] f32 (later: VT)
  u16*  S1T = (u16*) alloc(8388608);
  u16*  P2  = (u16*) alloc(8388608);
  u16*  P1  = (u16*)Am;                 // alias: Am dead after gemm<0>
  u16*  VT  = (u16*)S1;                 // alias: S1 dead after softmax2
  u16*  Am2 = (u16*)Am;                 // alias: P1 dead after k_tri

  k_v2m<<<1024, 256, 0, stream>>>(x, Am);
  k_w2m<<<1024, 256, 0, stream>>>(wq, wk, wv, wo, Bfo);
  k_mgemm<0><<<1536, 256, 0, stream>>>(Am, Bfo, qkv, nullptr, Nqp, Nkp);
  k_score<<<256, 256, 0, stream>>>(qkv, Nqp, Nkp, gamma, S1, S1T);
  k_softmax<<<2048, 256, 0, stream>>>(S1, mask, P1, 0);
  k_tri<<<256, 256, 0, stream>>>(P1, S1T, S1);
  k_softmax<<<2048, 256, 0, stream>>>(S1, mask, P2, 1);
  k_tr_v<<<512, 256, 0, stream>>>(qkv, VT);
  k_pv<<<512, 256, 0, stream>>>(P2, VT, Am2);
  k_mgemm<1><<<512, 256, 0, stream>>>(Am2, Bfo, nullptr, out, nullptr, nullptr);
}

// Round 14
// 300.978 us; speedup vs baseline: 2.4128x; 1.0280x over previous
//
#include <hip/hip_runtime.h>
#include <stdint.h>

typedef unsigned short u16;
typedef unsigned int u32;
typedef __attribute__((ext_vector_type(8))) __bf16 bf16x8;
typedef __attribute__((ext_vector_type(4))) float f32x4;

#define DEVINL __device__ __forceinline__

DEVINL float bf2f(u16 u){ union{u32 i; float f;} c; c.i = ((u32)u)<<16; return c.f; }
DEVINL u16 f2bf(float f){ union{float f; u32 i;} c; c.f=f; u32 u=c.i; return (u16)((u + 0x7fffu + ((u>>16)&1u))>>16); }
DEVINL u32 pack2(float a, float b){ return (u32)f2bf(a) | ((u32)f2bf(b)<<16); }

// parity of sign(e_a * e_b) in Cl(4,1) (used only for SIG_DIAG fold: sign of e_l^2)
DEVINL int sign_neg(int a, int b){
  int s = __popc((a>>1)&b) + __popc((a>>2)&b) + __popc((a>>3)&b) + __popc((a>>4)&b) + ((a&b)>>4);
  return s & 1;
}

// ---- Cl(4,1) -> M4(C) rep: blade I -> generalized permutation matrix:
// row r has single nonzero i^ph[I][r] at column col[I][r].
struct GTab { int col[32][4]; int ph[32][4]; };
constexpr GTab make_gtab(){
  GTab g{};
  int gc[5][4] = {}; int gp[5][4] = {};
  for (int r=0;r<4;r++){
    const int a=(r>>1)&1, b=r&1;
    gc[0][r]=r^2; gp[0][r]=0;                        // e0 = s1 x I
    gc[1][r]=r^2; gp[1][r]= a?1:3;                   // e1 = s2 x I
    gc[2][r]=r^1; gp[2][r]= a?2:0;                   // e2 = s3 x s1
    gc[3][r]=r^1; gp[3][r]=((a?2:0)+(b?1:3))&3;      // e3 = s3 x s2
    gc[4][r]=r;   gp[4][r]=(3+(a?2:0)+(b?2:0))&3;    // e4 = -i s3 x s3 (e4^2=-I)
  }
  for (int I=0;I<32;I++){
    for (int r=0;r<4;r++){ g.col[I][r]=r; g.ph[I][r]=0; }
    for (int bit=0;bit<5;bit++) if ((I>>bit)&1){
      for (int r=0;r<4;r++){
        const int c = g.col[I][r];
        g.ph[I][r]  = (g.ph[I][r] + gp[bit][c]) & 3;
        g.col[I][r] = gc[bit][c];
      }
    }
  }
  return g;
}
constexpr GTab GT = make_gtab();

// mv (32 reals) -> 4x4 complex matrix
DEVINL void mv2mat(const float (&x)[32], float (&Mre)[4][4], float (&Mim)[4][4]){
  #pragma unroll
  for (int r=0;r<4;r++)
    #pragma unroll
    for (int c=0;c<4;c++){ Mre[r][c]=0.f; Mim[r][c]=0.f; }
  #pragma unroll
  for (int l=0;l<32;l++){
    #pragma unroll
    for (int r=0;r<4;r++){
      constexpr const GTab& G = GT;
      const int c = G.col[l][r], p = G.ph[l][r];
      if (p==0) Mre[r][c] += x[l];
      else if (p==1) Mim[r][c] += x[l];
      else if (p==2) Mre[r][c] -= x[l];
      else Mim[r][c] -= x[l];
    }
  }
}

// v[c][r8] (r8<4: Re M[r8][c], r8>=4: Im M[r8-4][c]) -> mv
DEVINL void mat2mv(const float (&v)[4][8], float (&x)[32]){
  #pragma unroll
  for (int l=0;l<32;l++){
    float s = 0.f;
    #pragma unroll
    for (int r=0;r<4;r++){
      constexpr const GTab& G = GT;
      const int c = G.col[l][r], p = G.ph[l][r];
      if (p==0) s += v[c][r];
      else if (p==1) s += v[c][4+r];
      else if (p==2) s -= v[c][r];
      else s -= v[c][4+r];
    }
    x[l] = 0.25f*s;
  }
}

DEVINL void gload_lds16(const void* g, void* l){
  __builtin_amdgcn_global_load_lds(
    (const __attribute__((address_space(1))) void*)g,
    (__attribute__((address_space(3))) void*)l, 16, 0, 0);
}

// ---------------- x -> A-matrix: Am[(bs*4+c)][i*8+kk8] bf16 ----------------------
__global__ __launch_bounds__(256) void k_v2m(const float* __restrict__ x, u16* __restrict__ Am){
  const int bs = blockIdx.x, i = threadIdx.x;
  const float* xp = x + ((size_t)bs*256 + i)*32;
  float xv[32];
  #pragma unroll
  for (int q=0;q<8;q++){
    float4 v = *(const float4*)(xp + q*4);
    xv[q*4+0]=v.x; xv[q*4+1]=v.y; xv[q*4+2]=v.z; xv[q*4+3]=v.w;
  }
  float Mre[4][4], Mim[4][4];
  mv2mat(xv, Mre, Mim);
  #pragma unroll
  for (int c=0;c<4;c++){
    u32 w0 = pack2(Mre[0][c], Mre[1][c]);
    u32 w1 = pack2(Mre[2][c], Mre[3][c]);
    u32 w2 = pack2(Mim[0][c], Mim[1][c]);
    u32 w3 = pack2(Mim[2][c], Mim[3][c]);
    *(uint4*)(Am + ((size_t)(bs*4+c))*2048 + i*8) = make_uint4(w0,w1,w2,w3);
  }
}

// ---------------- w -> B fragment-order --------------------------------------------
// Bfo[sel][kq(32)][nblk(128)][kk(2)][lane(64)][e(8)]: value B[k][(o,r8)] = W8[o,i][r8][kk8]
// where n = o*8+r8 = nblk*16 + (lane&15), k = i*8+kk8 = kq*64 + kk*32 + (lane>>4)*8 + e
__global__ __launch_bounds__(256) void k_w2m(const float* __restrict__ wq, const float* __restrict__ wk,
                                             const float* __restrict__ wv, const float* __restrict__ wo,
                                             u16* __restrict__ Bfo){
  const int bid = blockIdx.x, i = threadIdx.x;
  const int wsel = bid>>8, o = bid&255;
  const float* w = wsel==0?wq: wsel==1?wk: wsel==2?wv: wo;
  const float* wp = w + ((size_t)o*256 + i)*32;
  float wv32[32];
  #pragma unroll
  for (int q=0;q<8;q++){
    float4 v = *(const float4*)(wp + q*4);
    wv32[q*4+0]=v.x; wv32[q*4+1]=v.y; wv32[q*4+2]=v.z; wv32[q*4+3]=v.w;
  }
  float Wre[4][4], Wim[4][4];
  mv2mat(wv32, Wre, Wim);
  u16* base = Bfo + (size_t)wsel*4194304 + (size_t)(i>>3)*131072 + (o>>1)*1024
            + ((i>>2)&1)*512;
  const int lanebase = (o&1)*8 + (i&3)*16;
  #pragma unroll
  for (int r8=0;r8<8;r8++){
    float e0,e1,e2,e3,e4,e5,e6,e7;
    if (r8<4){
      e0=Wre[r8][0]; e1=Wre[r8][1]; e2=Wre[r8][2]; e3=Wre[r8][3];
      e4=-Wim[r8][0]; e5=-Wim[r8][1]; e6=-Wim[r8][2]; e7=-Wim[r8][3];
    } else {
      e0=Wim[r8-4][0]; e1=Wim[r8-4][1]; e2=Wim[r8-4][2]; e3=Wim[r8-4][3];
      e4=Wre[r8-4][0]; e5=Wre[r8-4][1]; e6=Wre[r8-4][2]; e7=Wre[r8-4][3];
    }
    *(uint4*)(base + (lanebase + r8)*8) =
      make_uint4(pack2(e0,e1), pack2(e2,e3), pack2(e4,e5), pack2(e6,e7));
  }
}

// ---------------- matrix-basis GEMM: C = Am x Bfo, fused m2v epilogue --------------
// M=4096 (bs,c), K=2048 (i,kk8), N = 6144 (qkv) or 2048 (wo). 128x128 tile, 4 waves.
// T3-minimum 1-barrier pipeline: A double-buffered in LDS (stage t+1 issued after
// the barrier, covered by full compute phase); B reg-streamed; counted vmcnt(4).
template<int EPI>
__global__ __launch_bounds__(256) void k_mgemm(const u16* __restrict__ Am, const u16* __restrict__ Bfo,
                                               u16* __restrict__ qkv, float* __restrict__ dout,
                                               float* __restrict__ Nqp, float* __restrict__ Nkp){
  constexpr int NT = (EPI==0)?48:16;
  constexpr int NWG = 32*NT;
  __shared__ __align__(16) u16 SM[128*136];      // main loop: A buf0 [0,8192), buf1 [8192,16384) (u16 idx)
  const int wg = blockIdx.x;
  const int bid = (wg&7)*(NWG/8) + (wg>>3);      // bijective XCD chunking
  const int tn = bid>>5, tm = bid&31;            // tn-major: B panel per XCD
  const int row0 = tm*128, col0 = tn*128;
  const int sel   = (EPI==0)? (col0>>11) : 3;
  const int ncol0 = (EPI==0)? (col0&2047) : col0;
  const u16* Wsel = Bfo + (size_t)sel*4194304;
  const int t = threadIdx.x, lane = t&63, wid = t>>6;
  const int wm = wid>>1, wn = wid&1, lo = lane&15, hi = lane>>4;

  int boff[4][2];
  #pragma unroll
  for (int fn=0; fn<4; ++fn){
    const int nblk = (ncol0>>4) + wn*4 + fn;
    #pragma unroll
    for (int kk=0; kk<2; ++kk)
      boff[fn][kk] = (nblk*2+kk)*512 + lane*8;
  }

  f32x4 acc[4][4];
  #pragma unroll
  for(int a=0;a<4;a++){
    #pragma unroll
    for(int b=0;b<4;b++){ acc[a][b] = (f32x4){0.f,0.f,0.f,0.f}; }
  }

  // staging helper offsets
  const int sbase = (wid*4)*64;                  // this wave stages chunks wid*4..wid*4+3
  // prologue: stage A(0) into buf0
  #pragma unroll
  for (int cc=0;cc<4;cc++){
    const int base = sbase + cc*64;
    const int idx = base + lane;
    const int rr = idx>>3, g = idx&7;
    gload_lds16(Am + (size_t)(row0+rr)*2048 + ((g^(rr&7))*8), SM + base*8);
  }

  int cbuf = 0;
  for (int kq=0; kq<32; ++kq){
    // B fragment loads for tile kq (regs; compiler waits at first MFMA use)
    const u16* Wq = Wsel + (size_t)kq*131072;
    uint4 Br[8];
    #pragma unroll
    for (int fn=0; fn<4; ++fn){
      Br[fn*2+0] = *(const uint4*)(Wq + boff[fn][0]);
      Br[fn*2+1] = *(const uint4*)(Wq + boff[fn][1]);
    }
    // my A(kq) stage retired (4 oldest); newest stay in flight
    if (kq == 0) asm volatile("s_waitcnt vmcnt(8)" ::: "memory");
    else         asm volatile("s_waitcnt vmcnt(4)" ::: "memory");
    __builtin_amdgcn_sched_barrier(0);
    __builtin_amdgcn_s_barrier();                // all waves' A(kq) landed; buf^1 free
    __builtin_amdgcn_sched_barrier(0);
    // stage A(kq+1) into the other buffer (covered by this phase's compute)
    if (kq+1 < 32){
      #pragma unroll
      for (int cc=0;cc<4;cc++){
        const int base = sbase + cc*64;
        const int idx = base + lane;
        const int rr = idx>>3, g = idx&7;
        gload_lds16(Am + (size_t)(row0+rr)*2048 + (kq+1)*64 + ((g^(rr&7))*8),
                    SM + (cbuf^1)*8192 + base*8);
      }
    }
    const u16* Ab = SM + cbuf*8192;
    #pragma unroll
    for (int kk=0; kk<2; ++kk){
      bf16x8 af[4];
      #pragma unroll
      for (int f=0;f<4;f++){
        const int ra = wm*64 + f*16 + lo;
        const int jc = kk*4 + hi;
        af[f] = *(const bf16x8*)(Ab + ra*64 + ((jc^(ra&7))*8));
      }
      __builtin_amdgcn_s_setprio(1);
      #pragma unroll
      for (int fm=0;fm<4;fm++){
        #pragma unroll
        for (int fn=0;fn<4;fn++)
          acc[fm][fn] = __builtin_amdgcn_mfma_f32_16x16x32_bf16(
              af[fm], *(const bf16x8*)&Br[fn*2+kk], acc[fm][fn], 0,0,0);
      }
      __builtin_amdgcn_s_setprio(0);
    }
    cbuf ^= 1;
  }

  // ---- epilogue: dump C tile to LDS, reassemble multivectors, m2v + normalize ----
  __syncthreads();
  #pragma unroll
  for (int fm=0;fm<4;fm++){
    #pragma unroll
    for (int r=0;r<4;r++){
      const int mL = wm*64 + fm*16 + hi*4 + r;
      #pragma unroll
      for (int fn=0;fn<4;fn++){
        const int nL = wn*64 + fn*16 + lo;
        SM[mL*136 + nL] = f2bf(acc[fm][fn][r]);
      }
    }
  }
  __syncthreads();
  const int bsL = t>>3, oLp = t&7;
  const int bs = (row0>>2) + bsL;
  const int o0w = ncol0>>3;
  float nsum = 0.f;
  #pragma unroll
  for (int u=0;u<2;u++){
    const int oL = oLp + u*8;
    float v[4][8];
    #pragma unroll
    for (int c=0;c<4;c++){
      uint4 q4 = *(const uint4*)(SM + (bsL*4+c)*136 + oL*8);
      v[c][0]=bf2f((u16)(q4.x&0xffffu)); v[c][1]=bf2f((u16)(q4.x>>16));
      v[c][2]=bf2f((u16)(q4.y&0xffffu)); v[c][3]=bf2f((u16)(q4.y>>16));
      v[c][4]=bf2f((u16)(q4.z&0xffffu)); v[c][5]=bf2f((u16)(q4.z>>16));
      v[c][6]=bf2f((u16)(q4.w&0xffffu)); v[c][7]=bf2f((u16)(q4.w>>16));
    }
    float xs[32];
    mat2mv(v, xs);
    float s = 0.f;
    #pragma unroll
    for (int l=0;l<32;l++) s += xs[l]*xs[l];
    const float rs = rsqrtf(s + 1e-6f);
    if constexpr (EPI==0){
      nsum += s/(s+1e-6f);
      if (sel == 0){
        #pragma unroll
        for (int l=0;l<32;l++) xs[l] = sign_neg(l,l)? -xs[l]*rs : xs[l]*rs;
      } else {
        #pragma unroll
        for (int l=0;l<32;l++) xs[l] *= rs;
      }
      u16* dst = qkv + ((size_t)bs*768 + sel*256 + o0w + oL)*32;
      #pragma unroll
      for (int q=0;q<4;q++)
        *(uint4*)(dst + q*8) = make_uint4(pack2(xs[q*8+0],xs[q*8+1]), pack2(xs[q*8+2],xs[q*8+3]),
                                          pack2(xs[q*8+4],xs[q*8+5]), pack2(xs[q*8+6],xs[q*8+7]));
    } else {
      float* dst = dout + ((size_t)bs*256 + o0w + oL)*32;
      #pragma unroll
      for (int q=0;q<8;q++)
        *(float4*)(dst + q*4) = make_float4(xs[q*4+0]*rs, xs[q*4+1]*rs, xs[q*4+2]*rs, xs[q*4+3]*rs);
    }
  }
  if constexpr (EPI==0){
    if (sel < 2){
      nsum += __shfl_xor(nsum,1); nsum += __shfl_xor(nsum,2); nsum += __shfl_xor(nsum,4);
      if ((t&7)==0){
        const int half = (o0w>>4)&1, h = o0w>>5;
        const int b = bs>>9, s_ = bs&511;
        float* nd = (sel==0)? Nqp : Nkp;
        nd[half*8192 + (b*8+h)*512 + s_] = nsum;
      }
    }
  }
}

// ---------------- shared 128x128 MFMA tile engine (linear-row operands) -----------
DEVINL void mm_steps(const u16* Abase, int Astride, const u16* Bbase, int Bstride, int ksteps,
                     u16* Al, u16* Bl, f32x4 (&acc)[4][4], int lane, int wid){
  const int wm = wid>>1, wn = wid&1, lo = lane&15, hi = lane>>4;
  for (int s=0; s<ksteps; ++s){
    const int k0 = s*64;
    #pragma unroll
    for (int c=0;c<4;c++){
      const int gb = (wid*4+c)*64;
      const int idx = gb + lane;
      const int r = idx>>3, j = idx&7;
      const int sw = ((j^(r&7))*8);
      gload_lds16(Abase + (size_t)r*Astride + k0 + sw, Al + gb*8);
      gload_lds16(Bbase + (size_t)r*Bstride + k0 + sw, Bl + gb*8);
    }
    __syncthreads();
    #pragma unroll
    for (int kk=0; kk<2; ++kk){
      bf16x8 af[4], bfr[4];
      #pragma unroll
      for (int f=0;f<4;f++){
        const int ra = wm*64 + f*16 + lo;
        const int jc = kk*4 + hi;
        af[f] = *(const bf16x8*)(Al + ra*64 + ((jc^(ra&7))*8));
        const int rb = wn*64 + f*16 + lo;
        bfr[f] = *(const bf16x8*)(Bl + rb*64 + ((jc^(rb&7))*8));
      }
      #pragma unroll
      for (int fm=0;fm<4;fm++){
        #pragma unroll
        for (int fn=0;fn<4;fn++)
          acc[fm][fn] = __builtin_amdgcn_mfma_f32_16x16x32_bf16(af[fm], bfr[fn], acc[fm][fn], 0,0,0);
      }
    }
    __syncthreads();
  }
}

// ---------------- score: ss + gamma*bivector, write S1 f32 and S1T bf16 -----------
__global__ __launch_bounds__(256) void k_score(const u16* __restrict__ qkv, const float* __restrict__ Nqp,
                                               const float* __restrict__ Nkp, const float* __restrict__ gptr,
                                               float* __restrict__ S1, u16* __restrict__ S1T){
  __shared__ __align__(16) u16 Al[128*64];
  __shared__ __align__(16) u16 Bl[128*64];
  __shared__ __align__(16) u16 Tl[128*136];
  const int wg = blockIdx.x;
  const int bid = (wg&7)*32 + (wg>>3);
  const int bh = bid>>4, ti=(bid>>2)&3, tj=bid&3;
  const int b = bh>>3, h = bh&7;
  const int i0=ti*128, j0=tj*128;
  const int t=threadIdx.x, lane=t&63, wid=t>>6;
  const int wm=wid>>1, wn=wid&1, lo=lane&15, hi=lane>>4;
  f32x4 acc[4][4];
  #pragma unroll
  for(int a=0;a<4;a++){
    #pragma unroll
    for(int c=0;c<4;c++){ acc[a][c] = (f32x4){0.f,0.f,0.f,0.f}; }
  }
  const u16* Abase = qkv + ((size_t)(b*512+i0))*24576 + h*1024;
  const u16* Bbase = qkv + ((size_t)(b*512+j0))*24576 + 8192 + h*1024;
  mm_steps(Abase, 24576, Bbase, 24576, 16, Al, Bl, acc, lane, wid);
  const float gamma = *gptr;
  const float rhd = 0.17677669529663687f; // 1/sqrt(32)
  float nkv[4];
  #pragma unroll
  for (int fn=0;fn<4;fn++){
    const int idx = bh*512 + j0 + wn*64 + fn*16 + lo;
    nkv[fn] = Nkp[idx] + Nkp[8192 + idx];
  }
  #pragma unroll
  for (int fm=0;fm<4;fm++){
    #pragma unroll
    for (int r=0;r<4;r++){
      const int iL = wm*64 + fm*16 + hi*4 + r;
      const int qidx = bh*512 + i0 + iL;
      const float nq = Nqp[qidx] + Nqp[8192 + qidx];
      #pragma unroll
      for (int fn=0;fn<4;fn++){
        const int jL = wn*64 + fn*16 + lo;
        const float ss = acc[fm][fn][r];
        const float biv = sqrtf(fmaxf(nq*nkv[fn] - ss*ss, 0.f) + 1e-6f);
        const float sc = (ss + gamma*biv)*rhd;
        S1[((size_t)bh*512 + i0 + iL)*512 + j0 + jL] = sc;
        Tl[jL*136 + iL] = f2bf(sc);
      }
    }
  }
  __syncthreads();
  const int jj = t>>1, half = t&1;
  u16* dst = S1T + ((size_t)bh*512 + (j0+jj))*512 + i0 + half*64;
  #pragma unroll
  for (int q=0;q<8;q++)
    *(uint4*)(dst + q*8) = *(const uint4*)(Tl + jj*136 + half*64 + q*8);
}

// ---------------- row softmax, wave-per-row (optionally masked) -------------------
__global__ __launch_bounds__(256) void k_softmax(const float* __restrict__ S, const int* __restrict__ mask,
                                                 u16* __restrict__ P, int masked){
  const int t = threadIdx.x, lane = t&63, wid = t>>6;
  const int row = blockIdx.x*4 + wid;   // bh*512 + i
  const int b = row>>12;
  const float* sp = S + (size_t)row*512;
  float4 a = *(const float4*)(sp + lane*4);
  float4 c = *(const float4*)(sp + 256 + lane*4);
  if (masked){
    const int* mp = mask + b*512;
    int4 ma = *(const int4*)(mp + lane*4);
    int4 mc = *(const int4*)(mp + 256 + lane*4);
    if (ma.x==0) a.x=-1e9f; if (ma.y==0) a.y=-1e9f; if (ma.z==0) a.z=-1e9f; if (ma.w==0) a.w=-1e9f;
    if (mc.x==0) c.x=-1e9f; if (mc.y==0) c.y=-1e9f; if (mc.z==0) c.z=-1e9f; if (mc.w==0) c.w=-1e9f;
  }
  float mx = fmaxf(fmaxf(fmaxf(a.x,a.y),fmaxf(a.z,a.w)), fmaxf(fmaxf(c.x,c.y),fmaxf(c.z,c.w)));
  #pragma unroll
  for (int o=1;o<64;o<<=1) mx = fmaxf(mx, __shfl_xor(mx,o));
  const float e0=__expf(a.x-mx), e1=__expf(a.y-mx), e2=__expf(a.z-mx), e3=__expf(a.w-mx);
  const float e4=__expf(c.x-mx), e5=__expf(c.y-mx), e6=__expf(c.z-mx), e7=__expf(c.w-mx);
  float sm = (e0+e1)+(e2+e3)+(e4+e5)+(e6+e7);
  #pragma unroll
  for (int o=1;o<64;o<<=1) sm += __shfl_xor(sm,o);
  const float inv = 1.f/sm;
  u16* pp = P + (size_t)row*512;
  *(uint2*)(pp + lane*4)       = make_uint2(pack2(e0*inv,e1*inv), pack2(e2*inv,e3*inv));
  *(uint2*)(pp + 256 + lane*4) = make_uint2(pack2(e4*inv,e5*inv), pack2(e6*inv,e7*inv));
}

// ---------------- triangle update: S1 += 0.1 * P1 @ S1b (in place, f32) ----------
__global__ __launch_bounds__(256) void k_tri(const u16* __restrict__ P1, const u16* __restrict__ S1T,
                                             float* __restrict__ S1){
  __shared__ __align__(16) u16 Al[128*64];
  __shared__ __align__(16) u16 Bl[128*64];
  const int wg = blockIdx.x;
  const int bid = (wg&7)*32 + (wg>>3);
  const int bh = bid>>4, ti=(bid>>2)&3, tj=bid&3;
  const int i0=ti*128, j0=tj*128;
  const int t=threadIdx.x, lane=t&63, wid=t>>6;
  const int wm=wid>>1, wn=wid&1, lo=lane&15, hi=lane>>4;
  f32x4 acc[4][4];
  #pragma unroll
  for(int a=0;a<4;a++){
    #pragma unroll
    for(int c=0;c<4;c++){ acc[a][c] = (f32x4){0.f,0.f,0.f,0.f}; }
  }
  const u16* Abase = P1  + ((size_t)bh*512 + i0)*512;
  const u16* Bbase = S1T + ((size_t)bh*512 + j0)*512;
  mm_steps(Abase, 512, Bbase, 512, 8, Al, Bl, acc, lane, wid);
  #pragma unroll
  for (int fm=0;fm<4;fm++){
    #pragma unroll
    for (int r=0;r<4;r++){
      const int iL = wm*64 + fm*16 + hi*4 + r;
      #pragma unroll
      for (int fn=0;fn<4;fn++){
        const int jL = wn*64 + fn*16 + lo;
        const size_t idx = ((size_t)bh*512 + i0 + iL)*512 + j0 + jL;
        S1[idx] = S1[idx] + 0.1f*acc[fm][fn][r];
      }
    }
  }
}

// ---------------- transpose V to VT[bh][d][s] ------------------------------------
__global__ __launch_bounds__(256) void k_tr_v(const u16* __restrict__ qkv, u16* __restrict__ VT){
  __shared__ u16 tile[128*129];
  const int bid=blockIdx.x;
  const int bh = bid>>5, dch=(bid>>2)&7, sch=bid&3;
  const int b=bh>>3, h=bh&7;
  const int d0=dch*128, s0=sch*128;
  const int t=threadIdx.x;
  {
    const int r=t>>1, half=t&1;
    const u16* src = qkv + ((size_t)(b*512+s0+r))*24576 + 16384 + h*1024 + d0 + half*64;
    #pragma unroll
    for (int q=0;q<8;q++){
      uint4 v = *(const uint4*)(src + q*8);
      u16* dp = tile + r*129 + half*64 + q*8;
      dp[0]=(u16)(v.x&0xffffu); dp[1]=(u16)(v.x>>16); dp[2]=(u16)(v.y&0xffffu); dp[3]=(u16)(v.y>>16);
      dp[4]=(u16)(v.z&0xffffu); dp[5]=(u16)(v.z>>16); dp[6]=(u16)(v.w&0xffffu); dp[7]=(u16)(v.w>>16);
    }
  }
  __syncthreads();
  {
    const int rr=t>>1, half=t&1;
    u16* dst = VT + ((size_t)bh*1024 + d0+rr)*512 + s0 + half*64;
    #pragma unroll
    for (int q=0;q<4;q++){
      u32 w[8];
      #pragma unroll
      for (int e=0;e<8;e++){
        const int s = half*64 + q*16 + e*2;
        w[e] = (u32)tile[s*129+rr] | ((u32)tile[(s+1)*129+rr]<<16);
      }
      *(uint4*)(dst + q*16)     = make_uint4(w[0],w[1],w[2],w[3]);
      *(uint4*)(dst + q*16 + 8) = make_uint4(w[4],w[5],w[6],w[7]);
    }
  }
}

// ---------------- PV: out = P2 @ V, epilogue writes mat-basis Amat2 ---------------
__global__ __launch_bounds__(256) void k_pv(const u16* __restrict__ P2, const u16* __restrict__ VT,
                                            u16* __restrict__ Am2){
  __shared__ __align__(16) u16 Al[128*64];
  __shared__ __align__(16) u16 Bl[128*64];
  __shared__ __align__(16) u16 Tl[128*136];
  const int wg = blockIdx.x;
  const int bid = (wg&7)*64 + (wg>>3);
  const int bh = bid>>5, ti=(bid>>3)&3, td=bid&7;
  const int b=bh>>3, h=bh&7;
  const int i0=ti*128, d0=td*128;
  const int t=threadIdx.x, lane=t&63, wid=t>>6;
  const int wm=wid>>1, wn=wid&1, lo=lane&15, hi=lane>>4;
  f32x4 acc[4][4];
  #pragma unroll
  for(int a=0;a<4;a++){
    #pragma unroll
    for(int c=0;c<4;c++){ acc[a][c] = (f32x4){0.f,0.f,0.f,0.f}; }
  }
  const u16* Abase = P2 + ((size_t)bh*512 + i0)*512;
  const u16* Bbase = VT + ((size_t)bh*1024 + d0)*512;
  mm_steps(Abase, 512, Bbase, 512, 8, Al, Bl, acc, lane, wid);
  #pragma unroll
  for (int fm=0;fm<4;fm++){
    #pragma unroll
    for (int r=0;r<4;r++){
      const int sL = wm*64 + fm*16 + hi*4 + r;
      #pragma unroll
      for (int fn=0;fn<4;fn++){
        const int dL = wn*64 + fn*16 + lo;
        Tl[sL*136 + dL] = f2bf(acc[fm][fn][r]);
      }
    }
  }
  __syncthreads();
  // reassemble multivectors (128 s x 4 hd) and write A-matrix rows for gemm<1>
  #pragma unroll
  for (int u=0;u<2;u++){
    const int idx = t + u*256;
    const int sL = idx>>2, hdL = idx&3;
    const u16* tp = Tl + sL*136 + hdL*32;
    float xv[32];
    #pragma unroll
    for (int q=0;q<4;q++){
      uint4 v = *(const uint4*)(tp + q*8);
      xv[q*8+0]=bf2f((u16)(v.x&0xffffu)); xv[q*8+1]=bf2f((u16)(v.x>>16));
      xv[q*8+2]=bf2f((u16)(v.y&0xffffu)); xv[q*8+3]=bf2f((u16)(v.y>>16));
      xv[q*8+4]=bf2f((u16)(v.z&0xffffu)); xv[q*8+5]=bf2f((u16)(v.z>>16));
      xv[q*8+6]=bf2f((u16)(v.w&0xffffu)); xv[q*8+7]=bf2f((u16)(v.w>>16));
    }
    float Mre[4][4], Mim[4][4];
    mv2mat(xv, Mre, Mim);
    const int e = h*32 + td*4 + hdL;
    const size_t mrow = ((size_t)(b*512 + i0 + sL))*4;
    #pragma unroll
    for (int c=0;c<4;c++){
      u32 w0 = pack2(Mre[0][c], Mre[1][c]);
      u32 w1 = pack2(Mre[2][c], Mre[3][c]);
      u32 w2 = pack2(Mim[0][c], Mim[1][c]);
      u32 w3 = pack2(Mim[2][c], Mim[3][c]);
      *(uint4*)(Am2 + (mrow + c)*2048 + e*8) = make_uint4(w0,w1,w2,w3);
    }
  }
}

extern "C" void kernel_launch(void* const* d_in, const int* in_sizes, int n_in,
                              void* d_out, int out_size, void* d_ws, size_t ws_size,
                              hipStream_t stream) {
  const float* x  = (const float*)d_in[0];
  const float* wq = (const float*)d_in[1];
  const float* wk = (const float*)d_in[2];
  const float* wv = (const float*)d_in[3];
  const float* wo = (const float*)d_in[4];
  const float* gamma = (const float*)d_in[5];
  const int*   mask  = (const int*)d_in[6];
  float* out = (float*)d_out;

  char* ws = (char*)d_ws;
  size_t off = 0;
  auto alloc = [&](size_t n){ char* p = ws + off; off += (n + 255) & ~(size_t)255; return p; };
  u16*  Am  = (u16*) alloc(16777216);   // [4096][2048] bf16 (later: P1 8MB, then Am2)
  u16*  Bfo = (u16*) alloc(33554432);   // [4][32][128][2][64][8] bf16
  u16*  qkv = (u16*) alloc(50331648);   // [1024][768][32] bf16
  float* Nqp = (float*)alloc(65536);    // [2][8192]
  float* Nkp = (float*)alloc(65536);
  float* S1 = (float*)alloc(16777216);  // [16][512][512] f32 (later: VT)
  u16*  S1T = (u16*) alloc(8388608);
  u16*  P2  = (u16*) alloc(8388608);
  u16*  P1  = (u16*)Am;                 // alias: Am dead after gemm<0>
  u16*  VT  = (u16*)S1;                 // alias: S1 dead after softmax2
  u16*  Am2 = (u16*)Am;                 // alias: P1 dead after k_tri

  k_v2m<<<1024, 256, 0, stream>>>(x, Am);
  k_w2m<<<1024, 256, 0, stream>>>(wq, wk, wv, wo, Bfo);
  k_mgemm<0><<<1536, 256, 0, stream>>>(Am, Bfo, qkv, nullptr, Nqp, Nkp);
  k_score<<<256, 256, 0, stream>>>(qkv, Nqp, Nkp, gamma, S1, S1T);
  k_softmax<<<2048, 256, 0, stream>>>(S1, mask, P1, 0);
  k_tri<<<256, 256, 0, stream>>>(P1, S1T, S1);
  k_softmax<<<2048, 256, 0, stream>>>(S1, mask, P2, 1);
  k_tr_v<<<512, 256, 0, stream>>>(qkv, VT);
  k_pv<<<512, 256, 0, stream>>>(P2, VT, Am2);
  k_mgemm<1><<<512, 256, 0, stream>>>(Am2, Bfo, nullptr, out, nullptr, nullptr);
}